// Round 5
// baseline (1308.091 us; speedup 1.0000x reference)
//
#include <hip/hip_runtime.h>
#include <math.h>

#define NTOT   32768
#define DMODEL 256
#define EDGES  1048576
#define BGRAPH 128
#define NNODE  256
#define NHEAD  8
#define DHEAD  32
#define NLAYER 4
#define DIN    64

typedef short bf16x8 __attribute__((ext_vector_type(8)));
typedef float f32x4  __attribute__((ext_vector_type(4)));

__device__ __forceinline__ float bn_scale_c() { return 0.9999950000374997f; } // 1/sqrt(1+1e-5)

__device__ __forceinline__ unsigned short f2b(float f) {
    union { float f; unsigned int u; } v; v.f = f;
    unsigned int r = v.u + 0x7FFFu + ((v.u >> 16) & 1u);  // RNE
    return (unsigned short)(r >> 16);
}
__device__ __forceinline__ float b2f(unsigned short u) {
    union { unsigned int u; float f; } v; v.u = ((unsigned int)u) << 16;
    return v.f;
}

// ---------------------------------------------------------------------------
// CSR build (dst-indexed)
// ---------------------------------------------------------------------------
__global__ void k_hist(const int* __restrict__ dst, int* __restrict__ cnt) {
    int e = blockIdx.x * 256 + threadIdx.x;
    if (e < EDGES) atomicAdd(&cnt[dst[e]], 1);
}

__global__ void k_block_sum(const int* __restrict__ cnt, int* __restrict__ bsum) {
    __shared__ int s[256];
    int t = threadIdx.x;
    s[t] = cnt[blockIdx.x * 256 + t];
    __syncthreads();
    for (int o = 128; o > 0; o >>= 1) {
        if (t < o) s[t] += s[t + o];
        __syncthreads();
    }
    if (t == 0) bsum[blockIdx.x] = s[0];
}

__global__ void k_scan_bsum(int* __restrict__ bsum, int nb) {
    if (threadIdx.x == 0) {
        int run = 0;
        for (int i = 0; i < nb; ++i) { int v = bsum[i]; bsum[i] = run; run += v; }
    }
}

__global__ void k_scan_chunks(const int* __restrict__ cnt, const int* __restrict__ bsum,
                              int* __restrict__ rowptr) {
    __shared__ int s[256];
    int t = threadIdx.x;
    int gid = blockIdx.x * 256 + t;
    int v = cnt[gid];
    s[t] = v;
    __syncthreads();
    for (int o = 1; o < 256; o <<= 1) {
        int add = (t >= o) ? s[t - o] : 0;
        __syncthreads();
        s[t] += add;
        __syncthreads();
    }
    int incl = s[t];
    rowptr[gid] = bsum[blockIdx.x] + incl - v;   // exclusive
    if (gid == NTOT - 1) rowptr[NTOT] = bsum[blockIdx.x] + incl;
}

// scatter src & edge_attr into CSR order (drops perm indirection from hot loop)
__global__ void k_fill_csr(const int* __restrict__ src, const int* __restrict__ dst,
                           const float* __restrict__ ea, const int* __restrict__ rowptr,
                           int* __restrict__ cursor, int* __restrict__ sp,
                           float* __restrict__ eap) {
    int e = blockIdx.x * 256 + threadIdx.x;
    if (e >= EDGES) return;
    int d = dst[e];
    int pos = rowptr[d] + atomicAdd(&cursor[d], 1);
    sp[pos]  = src[e];
    eap[pos] = ea[e];
}

// ---------------------------------------------------------------------------
// fp32 -> bf16 elementwise (n % 4 == 0)
// ---------------------------------------------------------------------------
__global__ void k_f2b(const float* __restrict__ s, unsigned short* __restrict__ d, int n) {
    int i = (blockIdx.x * 256 + threadIdx.x) * 4;
    if (i >= n) return;
    float4 v = *(const float4*)(s + i);
    d[i + 0] = f2b(v.x); d[i + 1] = f2b(v.y); d[i + 2] = f2b(v.z); d[i + 3] = f2b(v.w);
}

// ---------------------------------------------------------------------------
// Weight convert + transpose: src[l][k][n] (fp32) -> dst[l][n][k] (bf16)
// ---------------------------------------------------------------------------
__global__ __launch_bounds__(256)
void k_convT(const float* __restrict__ src, unsigned short* __restrict__ dst, int K_, int N_) {
    __shared__ float tile[32][33];
    int l = blockIdx.z;
    int n0 = blockIdx.x * 32, k0 = blockIdx.y * 32;
    const float* s = src + (size_t)l * K_ * N_;
    unsigned short* d = dst + (size_t)l * N_ * K_;
    int tx = threadIdx.x & 31, ty = threadIdx.x >> 5;
#pragma unroll
    for (int i = 0; i < 32; i += 8)
        tile[ty + i][tx] = s[(size_t)(k0 + ty + i) * N_ + n0 + tx];
    __syncthreads();
#pragma unroll
    for (int i = 0; i < 32; i += 8)
        d[(size_t)(n0 + ty + i) * K_ + k0 + tx] = f2b(tile[tx][ty + i]);
}

// ---------------------------------------------------------------------------
// GINE aggregation, graph-local LDS gather.
// 2 blocks per graph, 512 threads. Stage the graph's 256 h-rows (128 KB bf16)
// into LDS linearly via global_load_lds; each wave owns 16 dst nodes; per edge
// the wave reads the src row from LDS (ds_read_b64, 4 dims/lane); (src, ea)
// broadcast via readlane. Metadata sp/eap are CSR-ordered coalesced streams.
// ---------------------------------------------------------------------------
__global__ __launch_bounds__(512)
void k_gine_agg(const unsigned short* __restrict__ hb,
                const int* __restrict__ rowptr,
                const int* __restrict__ sp, const float* __restrict__ eap,
                const float* __restrict__ ew, const float* __restrict__ eb,
                unsigned short* __restrict__ zb) {
    __shared__ unsigned short lds_h[NNODE * DMODEL];   // 128 KB
    int g = blockIdx.x >> 1, half = blockIdx.x & 1;
    int t = threadIdx.x;

    const unsigned short* gsrc = hb + (size_t)g * NNODE * DMODEL;
#pragma unroll
    for (int i = 0; i < 16; ++i) {
        int slot = i * 512 + t;
        __builtin_amdgcn_global_load_lds(
            (const __attribute__((address_space(1))) void*)(gsrc + slot * 8),
            (__attribute__((address_space(3))) void*)&lds_h[slot * 8], 16, 0, 0);
    }
    asm volatile("s_waitcnt vmcnt(0)" ::: "memory");
    __syncthreads();

    int w = t >> 6, lane = t & 63;
    int d0 = lane * 4;
    float4 ew4 = *(const float4*)&ew[d0];
    float4 eb4 = *(const float4*)&eb[d0];

    int n0 = g * NNODE + half * 128 + w * 16;
    for (int n = n0; n < n0 + 16; ++n) {
        int beg = rowptr[n], end = rowptr[n + 1];
        float a0 = 0.f, a1 = 0.f, a2 = 0.f, a3 = 0.f;
        for (int c = beg; c < end; c += 64) {
            int cnt = min(64, end - c);
            int sl_ = 0, avb_ = 0;
            if (lane < cnt) {
                sl_  = sp[c + lane] & (NNODE - 1);   // local node id (graphs node-aligned)
                avb_ = __float_as_int(eap[c + lane]);
            }
#pragma unroll 4
            for (int i = 0; i < cnt; ++i) {
                int   sl = __builtin_amdgcn_readlane(sl_, i);
                float av = __int_as_float(__builtin_amdgcn_readlane(avb_, i));
                uint2 hv = *(const uint2*)&lds_h[sl * DMODEL + d0];
                float t0 = fmaf(av, ew4.x, eb4.x);
                float t1 = fmaf(av, ew4.y, eb4.y);
                float t2 = fmaf(av, ew4.z, eb4.z);
                float t3 = fmaf(av, ew4.w, eb4.w);
                a0 += fmaxf(__uint_as_float(hv.x << 16) + t0, 0.f);
                a1 += fmaxf(__uint_as_float(hv.x & 0xffff0000u) + t1, 0.f);
                a2 += fmaxf(__uint_as_float(hv.y << 16) + t2, 0.f);
                a3 += fmaxf(__uint_as_float(hv.y & 0xffff0000u) + t3, 0.f);
            }
        }
        int ln = n & (NNODE - 1);
        uint2 hv = *(const uint2*)&lds_h[ln * DMODEL + d0];
        float z0 = __uint_as_float(hv.x << 16)         + a0;
        float z1 = __uint_as_float(hv.x & 0xffff0000u) + a1;
        float z2 = __uint_as_float(hv.y << 16)         + a2;
        float z3 = __uint_as_float(hv.y & 0xffff0000u) + a3;
        unsigned int lo, hi;
        asm("v_cvt_pk_bf16_f32 %0, %1, %2" : "=v"(lo) : "v"(z0), "v"(z1));
        asm("v_cvt_pk_bf16_f32 %0, %1, %2" : "=v"(hi) : "v"(z2), "v"(z3));
        uint2 pk; pk.x = lo; pk.y = hi;
        *(uint2*)&zb[(size_t)n * DMODEL + d0] = pk;
    }
}

// ---------------------------------------------------------------------------
// bf16 MFMA GEMM (m97 structure): C[M,N] = A[M,K] @ B[K,N]
// ---------------------------------------------------------------------------
template <int MODE, int WF32, int WB16>
__global__ __launch_bounds__(256)
void k_mm(const unsigned short* __restrict__ A, const unsigned short* __restrict__ Bt,
          const float* __restrict__ bias, const float* __restrict__ res,
          const float* __restrict__ add2, const float* __restrict__ g,
          const float* __restrict__ gb, float* __restrict__ Cf,
          unsigned short* __restrict__ Cb, int M, int N, int K) {
    const int BM = 128, BN = 128, BK = 32;
    __shared__ unsigned short As[BM * BK];
    __shared__ unsigned short Bs[BN * BK];

    int t = threadIdx.x;
    int w = t >> 6, l = t & 63;
    int wr = w >> 1, wc = w & 1;
    int bm = blockIdx.y * BM, bn = blockIdx.x * BN;

    f32x4 acc[4][4] = {};

    int rl = l & 15;
    int kc = l >> 4;

    for (int k0 = 0; k0 < K; k0 += BK) {
#pragma unroll
        for (int i = 0; i < 2; ++i) {
            int slot = i * 256 + t;
            int row = slot >> 2, kcc = slot & 3;
            const unsigned short* gp = A + (size_t)(bm + row) * K + k0 + kcc * 8;
            __builtin_amdgcn_global_load_lds(
                (const __attribute__((address_space(1))) void*)gp,
                (__attribute__((address_space(3))) void*)&As[(i * 256 + w * 64) * 8],
                16, 0, 0);
        }
#pragma unroll
        for (int i = 0; i < 2; ++i) {
            int slot = i * 256 + t;
            int row = slot >> 2, kcc = slot & 3;
            const unsigned short* gp = Bt + (size_t)(bn + row) * K + k0 + kcc * 8;
            __builtin_amdgcn_global_load_lds(
                (const __attribute__((address_space(1))) void*)gp,
                (__attribute__((address_space(3))) void*)&Bs[(i * 256 + w * 64) * 8],
                16, 0, 0);
        }
        asm volatile("s_waitcnt vmcnt(0)" ::: "memory");
        __syncthreads();

        bf16x8 av[4], bv[4];
#pragma unroll
        for (int m = 0; m < 4; ++m)
            av[m] = *(const bf16x8*)&As[(wr * 64 + m * 16 + rl) * BK + kc * 8];
#pragma unroll
        for (int n = 0; n < 4; ++n)
            bv[n] = *(const bf16x8*)&Bs[(wc * 64 + n * 16 + rl) * BK + kc * 8];
#pragma unroll
        for (int m = 0; m < 4; ++m)
#pragma unroll
            for (int n = 0; n < 4; ++n)
                acc[m][n] = __builtin_amdgcn_mfma_f32_16x16x32_bf16(av[m], bv[n], acc[m][n], 0, 0, 0);
        __syncthreads();
    }

    int rh = l >> 4;
#pragma unroll
    for (int n = 0; n < 4; ++n) {
        int col = bn + wc * 64 + n * 16 + rl;
        float bv_ = bias[col];
        float gs = 0.f, gbv = 0.f;
        if (MODE >= 2) { gs = g[col] * bn_scale_c(); gbv = gb[col]; }
#pragma unroll
        for (int m = 0; m < 4; ++m) {
#pragma unroll
            for (int j = 0; j < 4; ++j) {
                int row = bm + wr * 64 + m * 16 + rh * 4 + j;
                size_t idx = (size_t)row * N + col;
                float v = acc[m][n][j] + bv_;
                if (MODE == 1) v = fmaxf(v, 0.f);
                if (MODE >= 2) v = (v + res[idx]) * gs + gbv;
                if (MODE == 3) v += add2[idx];
                if (WF32) Cf[idx] = v;
                if (WB16) Cb[idx] = f2b(v);
            }
        }
    }
}

// ---------------------------------------------------------------------------
// MFMA attention, swapped-operand QK^T. Block = (graph b, head h). 4 waves x
// 64 q-rows. S = mfma(A=K_tile, B=Q) -> lane (rl,kc) holds
// S[q=rl][key=n*16+kc*4+j]: 4 consecutive keys -> packed b64 P stores,
// 2-shuffle softmax reductions. PV unchanged (contiguous b128 frag reads).
// ---------------------------------------------------------------------------
#define KP 40
#define VP 264
__global__ __launch_bounds__(256)
void k_attn(const unsigned short* __restrict__ qkv, unsigned short* __restrict__ o) {
    __shared__ unsigned short lds[10240 + 8448 + 16896]; // Ks | Vt | Ps (71168 B)
    unsigned short* Ks = lds;                 // [256][40]
    unsigned short* Vt = lds + 10240;         // [32][264]
    unsigned short* Ps = lds + 10240 + 8448;  // 4 x [16][264]

    int bh = blockIdx.x;
    int b = bh >> 3, h = bh & 7;
    int t = threadIdx.x;
    int w = t >> 6, l = t & 63;
    int rl = l & 15, kc = l >> 4;             // kc in [0,4)
    const float scale = 0.17677669529663687f; // 1/sqrt(32)

    const unsigned short* base = qkv + (size_t)b * NNODE * (3 * DMODEL);

    // ---- stage K: thread t = key row ----
    {
        const unsigned short* row = base + (size_t)t * (3 * DMODEL);
#pragma unroll
        for (int c = 0; c < 4; ++c) {
            bf16x8 kvv = *(const bf16x8*)(row + DMODEL + h * DHEAD + c * 8);
            *(bf16x8*)&Ks[t * KP + c * 8] = kvv;
        }
    }
    // ---- stage V^T: thread t -> keys k0..k0+3, dims d0..d0+7, b64 packed ----
    {
        int k0 = (t & 63) * 4, d0 = (t >> 6) * 8;
        bf16x8 vr[4];
#pragma unroll
        for (int i = 0; i < 4; ++i)
            vr[i] = *(const bf16x8*)(base + (size_t)(k0 + i) * (3 * DMODEL) + 2 * DMODEL + h * DHEAD + d0);
#pragma unroll
        for (int d = 0; d < 8; ++d) {
            ushort4 pk;
            pk.x = (unsigned short)vr[0][d];
            pk.y = (unsigned short)vr[1][d];
            pk.z = (unsigned short)vr[2][d];
            pk.w = (unsigned short)vr[3][d];
            *(ushort4*)&Vt[(d0 + d) * VP + k0] = pk;
        }
    }

    // ---- Q fragments (B-operand): lane (rl,kc): Q[qb+rl][kc*8..+7] ----
    bf16x8 qv[4];
#pragma unroll
    for (int m = 0; m < 4; ++m) {
        int q = w * 64 + m * 16 + rl;
        qv[m] = *(const bf16x8*)(base + (size_t)q * (3 * DMODEL) + h * DHEAD + kc * 8);
    }
    __syncthreads();

    unsigned short* Pw = Ps + w * 16 * VP;
    f32x4 zero = {0.f, 0.f, 0.f, 0.f};

#pragma unroll 1
    for (int m = 0; m < 4; ++m) {
        // ---- S^T tiles: s[n] = mfma(K_tile_n, Q) ----
        f32x4 s[16];
#pragma unroll
        for (int n = 0; n < 16; ++n) {
            bf16x8 kv = *(const bf16x8*)&Ks[(n * 16 + rl) * KP + kc * 8];
            s[n] = __builtin_amdgcn_mfma_f32_16x16x32_bf16(kv, qv[m], zero, 0, 0, 0);
        }
        // ---- softmax row q=rl (lane-local over n,j; reduce across kc) ----
        float mv = -1e30f;
#pragma unroll
        for (int n = 0; n < 16; ++n)
#pragma unroll
            for (int j = 0; j < 4; ++j) mv = fmaxf(mv, s[n][j]);
        mv = fmaxf(mv, __shfl_xor(mv, 16));
        mv = fmaxf(mv, __shfl_xor(mv, 32));
        float sumv = 0.f;
#pragma unroll
        for (int n = 0; n < 16; ++n) {
            float p0 = __expf((s[n][0] - mv) * scale);
            float p1 = __expf((s[n][1] - mv) * scale);
            float p2 = __expf((s[n][2] - mv) * scale);
            float p3 = __expf((s[n][3] - mv) * scale);
            sumv += (p0 + p1) + (p2 + p3);
            unsigned int lo, hi;
            asm("v_cvt_pk_bf16_f32 %0, %1, %2" : "=v"(lo) : "v"(p0), "v"(p1));
            asm("v_cvt_pk_bf16_f32 %0, %1, %2" : "=v"(hi) : "v"(p2), "v"(p3));
            uint2 pk; pk.x = lo; pk.y = hi;
            *(uint2*)&Pw[rl * VP + n * 16 + kc * 4] = pk;
        }
        sumv += __shfl_xor(sumv, 16);
        sumv += __shfl_xor(sumv, 32);

        // ---- O = P V : k = 256 keys in 8 steps ----
        f32x4 o0 = zero, o1 = zero;
#pragma unroll
        for (int ks = 0; ks < 8; ++ks) {
            bf16x8 pa = *(const bf16x8*)&Pw[rl * VP + ks * 32 + kc * 8];
            bf16x8 v0 = *(const bf16x8*)&Vt[rl * VP + ks * 32 + kc * 8];
            bf16x8 v1 = *(const bf16x8*)&Vt[(16 + rl) * VP + ks * 32 + kc * 8];
            o0 = __builtin_amdgcn_mfma_f32_16x16x32_bf16(pa, v0, o0, 0, 0, 0);
            o1 = __builtin_amdgcn_mfma_f32_16x16x32_bf16(pa, v1, o1, 0, 0, 0);
        }
        // ---- write O (normalized); row sums live at lane rl=q, fetch via shfl ----
#pragma unroll
        for (int j = 0; j < 4; ++j) {
            float sj = __shfl(sumv, kc * 4 + j);
            float inv = 1.f / sj;
            int q = w * 64 + m * 16 + kc * 4 + j;
            unsigned short* orow = o + ((size_t)b * NNODE + q) * DMODEL + h * DHEAD;
            orow[rl]      = f2b(o0[j] * inv);
            orow[16 + rl] = f2b(o1[j] * inv);
        }
    }
}

// ---------------------------------------------------------------------------
extern "C" void kernel_launch(void* const* d_in, const int* in_sizes, int n_in,
                              void* d_out, int out_size, void* d_ws, size_t ws_size,
                              hipStream_t stream) {
    const float* x          = (const float*)d_in[0];
    const float* edge_attr  = (const float*)d_in[1];
    const float* node_w     = (const float*)d_in[2];
    const float* node_b     = (const float*)d_in[3];
    const float* edge_w     = (const float*)d_in[4];
    const float* edge_b     = (const float*)d_in[5];
    const float* gine_w1    = (const float*)d_in[6];
    const float* gine_b1    = (const float*)d_in[7];
    const float* gine_w2    = (const float*)d_in[8];
    const float* gine_b2    = (const float*)d_in[9];
    const float* attn_in_w  = (const float*)d_in[10];
    const float* attn_in_b  = (const float*)d_in[11];
    const float* attn_out_w = (const float*)d_in[12];
    const float* attn_out_b = (const float*)d_in[13];
    const float* mlp_w1     = (const float*)d_in[14];
    const float* mlp_b1     = (const float*)d_in[15];
    const float* mlp_w2     = (const float*)d_in[16];
    const float* mlp_b2     = (const float*)d_in[17];
    const float* bn1_g      = (const float*)d_in[18];
    const float* bn1_b      = (const float*)d_in[19];
    const float* bn2_g      = (const float*)d_in[20];
    const float* bn2_b      = (const float*)d_in[21];
    const float* bn3_g      = (const float*)d_in[22];
    const float* bn3_b      = (const float*)d_in[23];
    const int*   edge_index = (const int*)d_in[24];

    const int* srcp = edge_index;
    const int* dstp = edge_index + EDGES;

    float* out = (float*)d_out;
    char*  ws  = (char*)d_ws;

    // ---- workspace layout ----
    size_t off = 0;
    float* hf    = (float*)(ws + off); off += (size_t)NTOT * DMODEL * 4;
    float* h1f   = (float*)(ws + off); off += (size_t)NTOT * DMODEL * 4;
    float* combf = (float*)(ws + off); off += (size_t)NTOT * DMODEL * 4;
    unsigned short* hb   = (unsigned short*)(ws + off); off += (size_t)NTOT * DMODEL * 2;
    unsigned short* bufA = (unsigned short*)(ws + off); off += (size_t)NTOT * 3 * DMODEL * 2;
    unsigned short* bufB = (unsigned short*)(ws + off); off += (size_t)NTOT * 2 * DMODEL * 2;
    unsigned short* xb   = (unsigned short*)(ws + off); off += (size_t)NTOT * DIN * 2;
    unsigned short* w_node = (unsigned short*)(ws + off); off += (size_t)DMODEL * DIN * 2;
    unsigned short* w_g1   = (unsigned short*)(ws + off); off += (size_t)NLAYER * DMODEL * DMODEL * 2;
    unsigned short* w_g2   = (unsigned short*)(ws + off); off += (size_t)NLAYER * DMODEL * DMODEL * 2;
    unsigned short* w_ai   = (unsigned short*)(ws + off); off += (size_t)NLAYER * 3 * DMODEL * DMODEL * 2;
    unsigned short* w_ao   = (unsigned short*)(ws + off); off += (size_t)NLAYER * DMODEL * DMODEL * 2;
    unsigned short* w_m1   = (unsigned short*)(ws + off); off += (size_t)NLAYER * 2 * DMODEL * DMODEL * 2;
    unsigned short* w_m2   = (unsigned short*)(ws + off); off += (size_t)NLAYER * 2 * DMODEL * DMODEL * 2;
    int*   rowptr = (int*)(ws + off);   off += ((size_t)NTOT + 4) * 4;
    int*   sp     = (int*)(ws + off);   off += (size_t)EDGES * 4;
    float* eap    = (float*)(ws + off); off += (size_t)EDGES * 4;
    int*   cnt    = (int*)(ws + off);   off += (size_t)NTOT * 4;
    int*   bsum   = (int*)(ws + off);   off += 128 * 4;
    (void)ws_size; (void)in_sizes; (void)n_in; (void)out_size;

    // ---- CSR build ----
    hipMemsetAsync(cnt, 0, (size_t)NTOT * 4, stream);
    k_hist<<<EDGES / 256, 256, 0, stream>>>(dstp, cnt);
    k_block_sum<<<NTOT / 256, 256, 0, stream>>>(cnt, bsum);
    k_scan_bsum<<<1, 64, 0, stream>>>(bsum, NTOT / 256);
    k_scan_chunks<<<NTOT / 256, 256, 0, stream>>>(cnt, bsum, rowptr);
    hipMemsetAsync(cnt, 0, (size_t)NTOT * 4, stream);
    k_fill_csr<<<EDGES / 256, 256, 0, stream>>>(srcp, dstp, edge_attr, rowptr, cnt, sp, eap);

    // ---- weight & input conversion ----
    k_f2b<<<NTOT * DIN / 4 / 256, 256, 0, stream>>>(x, xb, NTOT * DIN);
    k_convT<<<dim3(DMODEL / 32, DIN / 32, 1), 256, 0, stream>>>(node_w, w_node, DIN, DMODEL);
    k_convT<<<dim3(DMODEL / 32, DMODEL / 32, NLAYER), 256, 0, stream>>>(gine_w1, w_g1, DMODEL, DMODEL);
    k_convT<<<dim3(DMODEL / 32, DMODEL / 32, NLAYER), 256, 0, stream>>>(gine_w2, w_g2, DMODEL, DMODEL);
    k_convT<<<dim3(3 * DMODEL / 32, DMODEL / 32, NLAYER), 256, 0, stream>>>(attn_in_w, w_ai, DMODEL, 3 * DMODEL);
    k_convT<<<dim3(DMODEL / 32, DMODEL / 32, NLAYER), 256, 0, stream>>>(attn_out_w, w_ao, DMODEL, DMODEL);
    k_convT<<<dim3(2 * DMODEL / 32, DMODEL / 32, NLAYER), 256, 0, stream>>>(mlp_w1, w_m1, DMODEL, 2 * DMODEL);
    k_convT<<<dim3(DMODEL / 32, 2 * DMODEL / 32, NLAYER), 256, 0, stream>>>(mlp_w2, w_m2, 2 * DMODEL, DMODEL);

    // ---- encoder ----
    k_mm<0, 1, 1><<<dim3(DMODEL / 128, NTOT / 128), 256, 0, stream>>>(
        xb, w_node, node_b, nullptr, nullptr, nullptr, nullptr, hf, hb, NTOT, DMODEL, DIN);

    for (int l = 0; l < NLAYER; ++l) {
        const unsigned short* g1 = w_g1 + (size_t)l * DMODEL * DMODEL;
        const unsigned short* g2 = w_g2 + (size_t)l * DMODEL * DMODEL;
        const unsigned short* ai = w_ai + (size_t)l * 3 * DMODEL * DMODEL;
        const unsigned short* ao = w_ao + (size_t)l * DMODEL * DMODEL;
        const unsigned short* m1 = w_m1 + (size_t)l * 2 * DMODEL * DMODEL;
        const unsigned short* m2 = w_m2 + (size_t)l * 2 * DMODEL * DMODEL;

        unsigned short* zb   = bufA;
        unsigned short* hidb = bufB;
        unsigned short* qkvb = bufA;
        unsigned short* ob   = bufB;
        unsigned short* cmbb = bufA;
        unsigned short* h5b  = bufB;

        k_gine_agg<<<BGRAPH * 2, 512, 0, stream>>>(hb, rowptr, sp, eap,
                                                   edge_w, edge_b, zb);
        k_mm<1, 0, 1><<<dim3(2, NTOT / 128), 256, 0, stream>>>(
            zb, g1, gine_b1 + (size_t)l * DMODEL, nullptr, nullptr, nullptr, nullptr,
            nullptr, hidb, NTOT, DMODEL, DMODEL);
        k_mm<2, 1, 0><<<dim3(2, NTOT / 128), 256, 0, stream>>>(
            hidb, g2, gine_b2 + (size_t)l * DMODEL, hf, nullptr,
            bn1_g + (size_t)l * DMODEL, bn1_b + (size_t)l * DMODEL,
            h1f, nullptr, NTOT, DMODEL, DMODEL);

        k_mm<0, 0, 1><<<dim3(6, NTOT / 128), 256, 0, stream>>>(
            hb, ai, attn_in_b + (size_t)l * 3 * DMODEL, nullptr, nullptr, nullptr, nullptr,
            nullptr, qkvb, NTOT, 3 * DMODEL, DMODEL);
        k_attn<<<BGRAPH * NHEAD, 256, 0, stream>>>(qkvb, ob);
        k_mm<3, 1, 1><<<dim3(2, NTOT / 128), 256, 0, stream>>>(
            ob, ao, attn_out_b + (size_t)l * DMODEL, hf, h1f,
            bn2_g + (size_t)l * DMODEL, bn2_b + (size_t)l * DMODEL,
            combf, cmbb, NTOT, DMODEL, DMODEL);

        k_mm<1, 0, 1><<<dim3(4, NTOT / 128), 256, 0, stream>>>(
            cmbb, m1, mlp_b1 + (size_t)l * 2 * DMODEL, nullptr, nullptr, nullptr, nullptr,
            nullptr, h5b, NTOT, 2 * DMODEL, DMODEL);
        float* dest = (l == NLAYER - 1) ? out : hf;
        k_mm<2, 1, 1><<<dim3(2, NTOT / 128), 256, 0, stream>>>(
            h5b, m2, mlp_b2 + (size_t)l * DMODEL, combf, nullptr,
            bn3_g + (size_t)l * DMODEL, bn3_b + (size_t)l * DMODEL,
            dest, hb, NTOT, DMODEL, 2 * DMODEL);
    }
}

// Round 6
// 1150.391 us; speedup vs baseline: 1.1371x; 1.1371x over previous
//
#include <hip/hip_runtime.h>
#include <math.h>

#define NTOT   32768
#define DMODEL 256
#define EDGES  1048576
#define BGRAPH 128
#define NNODE  256
#define NHEAD  8
#define DHEAD  32
#define NLAYER 4
#define DIN    64
#define BNS    0.9999950000374997f   // 1/sqrt(1+1e-5)

typedef short bf16x8 __attribute__((ext_vector_type(8)));
typedef float f32x4  __attribute__((ext_vector_type(4)));

__device__ __forceinline__ unsigned short f2b(float f) {
    union { float f; unsigned int u; } v; v.f = f;
    unsigned int r = v.u + 0x7FFFu + ((v.u >> 16) & 1u);  // RNE
    return (unsigned short)(r >> 16);
}
__device__ __forceinline__ float b2f(unsigned short u) {
    union { unsigned int u; float f; } v; v.u = ((unsigned int)u) << 16;
    return v.f;
}

// ---------------------------------------------------------------------------
// CSR build (dst-indexed)
// ---------------------------------------------------------------------------
__global__ void k_hist(const int* __restrict__ dst, int* __restrict__ cnt) {
    int e = blockIdx.x * 256 + threadIdx.x;
    if (e < EDGES) atomicAdd(&cnt[dst[e]], 1);
}

__global__ void k_block_sum(const int* __restrict__ cnt, int* __restrict__ bsum) {
    __shared__ int s[256];
    int t = threadIdx.x;
    s[t] = cnt[blockIdx.x * 256 + t];
    __syncthreads();
    for (int o = 128; o > 0; o >>= 1) {
        if (t < o) s[t] += s[t + o];
        __syncthreads();
    }
    if (t == 0) bsum[blockIdx.x] = s[0];
}

__global__ void k_scan_bsum(int* __restrict__ bsum, int nb) {
    if (threadIdx.x == 0) {
        int run = 0;
        for (int i = 0; i < nb; ++i) { int v = bsum[i]; bsum[i] = run; run += v; }
    }
}

__global__ void k_scan_chunks(const int* __restrict__ cnt, const int* __restrict__ bsum,
                              int* __restrict__ rowptr) {
    __shared__ int s[256];
    int t = threadIdx.x;
    int gid = blockIdx.x * 256 + t;
    int v = cnt[gid];
    s[t] = v;
    __syncthreads();
    for (int o = 1; o < 256; o <<= 1) {
        int add = (t >= o) ? s[t - o] : 0;
        __syncthreads();
        s[t] += add;
        __syncthreads();
    }
    int incl = s[t];
    rowptr[gid] = bsum[blockIdx.x] + incl - v;   // exclusive
    if (gid == NTOT - 1) rowptr[NTOT] = bsum[blockIdx.x] + incl;
}

// scatter src & edge_attr into CSR order
__global__ void k_fill_csr(const int* __restrict__ src, const int* __restrict__ dst,
                           const float* __restrict__ ea, const int* __restrict__ rowptr,
                           int* __restrict__ cursor, int* __restrict__ sp,
                           float* __restrict__ eap) {
    int e = blockIdx.x * 256 + threadIdx.x;
    if (e >= EDGES) return;
    int d = dst[e];
    int pos = rowptr[d] + atomicAdd(&cursor[d], 1);
    sp[pos]  = src[e];
    eap[pos] = ea[e];
}

// ---------------------------------------------------------------------------
// fp32 -> bf16 elementwise (n % 4 == 0)
// ---------------------------------------------------------------------------
__global__ void k_f2b(const float* __restrict__ s, unsigned short* __restrict__ d, int n) {
    int i = (blockIdx.x * 256 + threadIdx.x) * 4;
    if (i >= n) return;
    float4 v = *(const float4*)(s + i);
    d[i + 0] = f2b(v.x); d[i + 1] = f2b(v.y); d[i + 2] = f2b(v.z); d[i + 3] = f2b(v.w);
}

// ---------------------------------------------------------------------------
// Weight convert + transpose (+optional per-output-col BN scale fold):
// src[l][k][n] fp32 -> dst[l][n][koff + k] bf16, dst row stride Kdst.
// scale (if set): dst val *= scale[l*N_ + n] * BNS.
// ---------------------------------------------------------------------------
__global__ __launch_bounds__(256)
void k_convT(const float* __restrict__ src, unsigned short* __restrict__ dst, int K_, int N_,
             const float* __restrict__ scale, int Kdst, int koff) {
    __shared__ float tile[32][33];
    int l = blockIdx.z;
    int n0 = blockIdx.x * 32, k0 = blockIdx.y * 32;
    const float* s = src + (size_t)l * K_ * N_;
    unsigned short* d = dst + (size_t)l * N_ * Kdst;
    int tx = threadIdx.x & 31, ty = threadIdx.x >> 5;
#pragma unroll
    for (int i = 0; i < 32; i += 8)
        tile[ty + i][tx] = s[(size_t)(k0 + ty + i) * N_ + n0 + tx];
    __syncthreads();
#pragma unroll
    for (int i = 0; i < 32; i += 8) {
        int n = n0 + ty + i;
        float sc = scale ? scale[(size_t)l * N_ + n] * BNS : 1.f;
        d[(size_t)n * Kdst + koff + k0 + tx] = f2b(tile[tx][ty + i] * sc);
    }
}

// ---------------------------------------------------------------------------
// Per-layer fused epilogue vectors:
// biasC = gb2*s1 + t1 + aob*s2 + t2 ; rC = s1+s2
// biasF = mb2*s3 + t3               ; rF = s3
// ---------------------------------------------------------------------------
__global__ void k_mkvec(const float* __restrict__ bn1_g, const float* __restrict__ bn1_b,
                        const float* __restrict__ bn2_g, const float* __restrict__ bn2_b,
                        const float* __restrict__ bn3_g, const float* __restrict__ bn3_b,
                        const float* __restrict__ gb2, const float* __restrict__ aob,
                        const float* __restrict__ mb2,
                        float* __restrict__ biasC, float* __restrict__ rC,
                        float* __restrict__ biasF, float* __restrict__ rF) {
    int i = blockIdx.x * 256 + threadIdx.x;
    float s1 = bn1_g[i] * BNS, t1 = bn1_b[i];
    float s2 = bn2_g[i] * BNS, t2 = bn2_b[i];
    float s3 = bn3_g[i] * BNS, t3 = bn3_b[i];
    biasC[i] = gb2[i] * s1 + t1 + aob[i] * s2 + t2;
    rC[i]    = s1 + s2;
    biasF[i] = mb2[i] * s3 + t3;
    rF[i]    = s3;
}

// ---------------------------------------------------------------------------
// GINE aggregation, graph-local LDS gather, 1024 threads (16 waves).
// 2 blocks/graph; both stage the full graph h (2nd stage hits L2); each block
// owns 128 dst nodes (8 per wave). Per edge: wave reads src row from LDS.
// ---------------------------------------------------------------------------
__global__ __launch_bounds__(1024)
void k_gine_agg(const unsigned short* __restrict__ hb,
                const int* __restrict__ rowptr,
                const int* __restrict__ sp, const float* __restrict__ eap,
                const float* __restrict__ ew, const float* __restrict__ eb,
                unsigned short* __restrict__ zb) {
    __shared__ unsigned short lds_h[NNODE * DMODEL];   // 128 KB
    int g = blockIdx.x >> 1, half = blockIdx.x & 1;
    int t = threadIdx.x;

    const unsigned short* gsrc = hb + (size_t)g * NNODE * DMODEL;
#pragma unroll
    for (int i = 0; i < 8; ++i) {
        int slot = i * 1024 + t;
        __builtin_amdgcn_global_load_lds(
            (const __attribute__((address_space(1))) void*)(gsrc + slot * 8),
            (__attribute__((address_space(3))) void*)&lds_h[slot * 8], 16, 0, 0);
    }
    asm volatile("s_waitcnt vmcnt(0)" ::: "memory");
    __syncthreads();

    int w = t >> 6, lane = t & 63;
    int d0 = lane * 4;
    float4 ew4 = *(const float4*)&ew[d0];
    float4 eb4 = *(const float4*)&eb[d0];

    int n0 = g * NNODE + half * 128 + w * 8;
    for (int n = n0; n < n0 + 8; ++n) {
        int beg = rowptr[n], end = rowptr[n + 1];
        float a0 = 0.f, a1 = 0.f, a2 = 0.f, a3 = 0.f;
        for (int c = beg; c < end; c += 64) {
            int cnt = min(64, end - c);
            int sl_ = 0, avb_ = 0;
            if (lane < cnt) {
                sl_  = sp[c + lane] & (NNODE - 1);   // local node id
                avb_ = __float_as_int(eap[c + lane]);
            }
#pragma unroll 4
            for (int i = 0; i < cnt; ++i) {
                int   sl = __builtin_amdgcn_readlane(sl_, i);
                float av = __int_as_float(__builtin_amdgcn_readlane(avb_, i));
                uint2 hv = *(const uint2*)&lds_h[sl * DMODEL + d0];
                float t0 = fmaf(av, ew4.x, eb4.x);
                float t1 = fmaf(av, ew4.y, eb4.y);
                float t2 = fmaf(av, ew4.z, eb4.z);
                float t3 = fmaf(av, ew4.w, eb4.w);
                a0 += fmaxf(__uint_as_float(hv.x << 16) + t0, 0.f);
                a1 += fmaxf(__uint_as_float(hv.x & 0xffff0000u) + t1, 0.f);
                a2 += fmaxf(__uint_as_float(hv.y << 16) + t2, 0.f);
                a3 += fmaxf(__uint_as_float(hv.y & 0xffff0000u) + t3, 0.f);
            }
        }
        int ln = n & (NNODE - 1);
        uint2 hv = *(const uint2*)&lds_h[ln * DMODEL + d0];
        float z0 = __uint_as_float(hv.x << 16)         + a0;
        float z1 = __uint_as_float(hv.x & 0xffff0000u) + a1;
        float z2 = __uint_as_float(hv.y << 16)         + a2;
        float z3 = __uint_as_float(hv.y & 0xffff0000u) + a3;
        unsigned int lo, hi;
        asm("v_cvt_pk_bf16_f32 %0, %1, %2" : "=v"(lo) : "v"(z0), "v"(z1));
        asm("v_cvt_pk_bf16_f32 %0, %1, %2" : "=v"(hi) : "v"(z2), "v"(z3));
        uint2 pk; pk.x = lo; pk.y = hi;
        *(uint2*)&zb[(size_t)n * DMODEL + d0] = pk;
    }
}

// ---------------------------------------------------------------------------
// bf16 MFMA GEMM: C[M,N] = A[M,K] @ Bt[N,K]^T, C row stride ldc.
// MODE 0: +bias   1: relu(+bias)   4: +bias + rvec[col]*res_bf16[row,col]
// Cb (bf16) always written; Cf (fp32) written if non-null.
// ---------------------------------------------------------------------------
template <int MODE>
__global__ __launch_bounds__(256)
void k_mm(const unsigned short* __restrict__ A, const unsigned short* __restrict__ Bt,
          const float* __restrict__ bias, const float* __restrict__ rvec,
          const unsigned short* __restrict__ resb, float* __restrict__ Cf,
          unsigned short* __restrict__ Cb, int M, int N, int K, int ldc) {
    const int BM = 128, BN = 128, BK = 32;
    __shared__ unsigned short As[BM * BK];
    __shared__ unsigned short Bs[BN * BK];

    int t = threadIdx.x;
    int w = t >> 6, l = t & 63;
    int wr = w >> 1, wc = w & 1;
    int bm = blockIdx.y * BM, bn = blockIdx.x * BN;

    f32x4 acc[4][4] = {};

    int rl = l & 15;
    int kc = l >> 4;

    for (int k0 = 0; k0 < K; k0 += BK) {
#pragma unroll
        for (int i = 0; i < 2; ++i) {
            int slot = i * 256 + t;
            int row = slot >> 2, kcc = slot & 3;
            const unsigned short* gp = A + (size_t)(bm + row) * K + k0 + kcc * 8;
            __builtin_amdgcn_global_load_lds(
                (const __attribute__((address_space(1))) void*)gp,
                (__attribute__((address_space(3))) void*)&As[(i * 256 + w * 64) * 8],
                16, 0, 0);
        }
#pragma unroll
        for (int i = 0; i < 2; ++i) {
            int slot = i * 256 + t;
            int row = slot >> 2, kcc = slot & 3;
            const unsigned short* gp = Bt + (size_t)(bn + row) * K + k0 + kcc * 8;
            __builtin_amdgcn_global_load_lds(
                (const __attribute__((address_space(1))) void*)gp,
                (__attribute__((address_space(3))) void*)&Bs[(i * 256 + w * 64) * 8],
                16, 0, 0);
        }
        asm volatile("s_waitcnt vmcnt(0)" ::: "memory");
        __syncthreads();

        bf16x8 av[4], bv[4];
#pragma unroll
        for (int m = 0; m < 4; ++m)
            av[m] = *(const bf16x8*)&As[(wr * 64 + m * 16 + rl) * BK + kc * 8];
#pragma unroll
        for (int n = 0; n < 4; ++n)
            bv[n] = *(const bf16x8*)&Bs[(wc * 64 + n * 16 + rl) * BK + kc * 8];
#pragma unroll
        for (int m = 0; m < 4; ++m)
#pragma unroll
            for (int n = 0; n < 4; ++n)
                acc[m][n] = __builtin_amdgcn_mfma_f32_16x16x32_bf16(av[m], bv[n], acc[m][n], 0, 0, 0);
        __syncthreads();
    }

    int rh = l >> 4;
#pragma unroll
    for (int n = 0; n < 4; ++n) {
        int col = bn + wc * 64 + n * 16 + rl;
        float bv_ = bias[col];
        float rv = 0.f;
        if (MODE == 4) rv = rvec[col];
#pragma unroll
        for (int m = 0; m < 4; ++m) {
#pragma unroll
            for (int j = 0; j < 4; ++j) {
                int row = bm + wr * 64 + m * 16 + rh * 4 + j;
                size_t idx = (size_t)row * ldc + col;
                float v = acc[m][n][j] + bv_;
                if (MODE == 1) v = fmaxf(v, 0.f);
                if (MODE == 4) v += rv * b2f(resb[idx]);
                if (Cf) Cf[idx] = v;
                Cb[idx] = f2b(v);
            }
        }
    }
}

// ---------------------------------------------------------------------------
// MFMA attention, swapped-operand QK^T. Output written into the concat buffer
// [M,512] at column offset 256 (row stride 512).
// ---------------------------------------------------------------------------
#define KP 40
#define VP 264
#define OSTR 512
#define OOFF 256
__global__ __launch_bounds__(256)
void k_attn(const unsigned short* __restrict__ qkv, unsigned short* __restrict__ o) {
    __shared__ unsigned short lds[10240 + 8448 + 16896]; // Ks | Vt | Ps (71168 B)
    unsigned short* Ks = lds;                 // [256][40]
    unsigned short* Vt = lds + 10240;         // [32][264]
    unsigned short* Ps = lds + 10240 + 8448;  // 4 x [16][264]

    int bh = blockIdx.x;
    int b = bh >> 3, h = bh & 7;
    int t = threadIdx.x;
    int w = t >> 6, l = t & 63;
    int rl = l & 15, kc = l >> 4;             // kc in [0,4)
    const float scale = 0.17677669529663687f; // 1/sqrt(32)

    const unsigned short* base = qkv + (size_t)b * NNODE * (3 * DMODEL);

    // ---- stage K: thread t = key row ----
    {
        const unsigned short* row = base + (size_t)t * (3 * DMODEL);
#pragma unroll
        for (int c = 0; c < 4; ++c) {
            bf16x8 kvv = *(const bf16x8*)(row + DMODEL + h * DHEAD + c * 8);
            *(bf16x8*)&Ks[t * KP + c * 8] = kvv;
        }
    }
    // ---- stage V^T: thread t -> keys k0..k0+3, dims d0..d0+7 ----
    {
        int k0 = (t & 63) * 4, d0 = (t >> 6) * 8;
        bf16x8 vr[4];
#pragma unroll
        for (int i = 0; i < 4; ++i)
            vr[i] = *(const bf16x8*)(base + (size_t)(k0 + i) * (3 * DMODEL) + 2 * DMODEL + h * DHEAD + d0);
#pragma unroll
        for (int d = 0; d < 8; ++d) {
            ushort4 pk;
            pk.x = (unsigned short)vr[0][d];
            pk.y = (unsigned short)vr[1][d];
            pk.z = (unsigned short)vr[2][d];
            pk.w = (unsigned short)vr[3][d];
            *(ushort4*)&Vt[(d0 + d) * VP + k0] = pk;
        }
    }

    // ---- Q fragments (B-operand) ----
    bf16x8 qv[4];
#pragma unroll
    for (int m = 0; m < 4; ++m) {
        int q = w * 64 + m * 16 + rl;
        qv[m] = *(const bf16x8*)(base + (size_t)q * (3 * DMODEL) + h * DHEAD + kc * 8);
    }
    __syncthreads();

    unsigned short* Pw = Ps + w * 16 * VP;
    f32x4 zero = {0.f, 0.f, 0.f, 0.f};

#pragma unroll 1
    for (int m = 0; m < 4; ++m) {
        f32x4 s[16];
#pragma unroll
        for (int n = 0; n < 16; ++n) {
            bf16x8 kv = *(const bf16x8*)&Ks[(n * 16 + rl) * KP + kc * 8];
            s[n] = __builtin_amdgcn_mfma_f32_16x16x32_bf16(kv, qv[m], zero, 0, 0, 0);
        }
        float mv = -1e30f;
#pragma unroll
        for (int n = 0; n < 16; ++n)
#pragma unroll
            for (int j = 0; j < 4; ++j) mv = fmaxf(mv, s[n][j]);
        mv = fmaxf(mv, __shfl_xor(mv, 16));
        mv = fmaxf(mv, __shfl_xor(mv, 32));
        float sumv = 0.f;
#pragma unroll
        for (int n = 0; n < 16; ++n) {
            float p0 = __expf((s[n][0] - mv) * scale);
            float p1 = __expf((s[n][1] - mv) * scale);
            float p2 = __expf((s[n][2] - mv) * scale);
            float p3 = __expf((s[n][3] - mv) * scale);
            sumv += (p0 + p1) + (p2 + p3);
            unsigned int lo, hi;
            asm("v_cvt_pk_bf16_f32 %0, %1, %2" : "=v"(lo) : "v"(p0), "v"(p1));
            asm("v_cvt_pk_bf16_f32 %0, %1, %2" : "=v"(hi) : "v"(p2), "v"(p3));
            uint2 pk; pk.x = lo; pk.y = hi;
            *(uint2*)&Pw[rl * VP + n * 16 + kc * 4] = pk;
        }
        sumv += __shfl_xor(sumv, 16);
        sumv += __shfl_xor(sumv, 32);

        f32x4 o0 = zero, o1 = zero;
#pragma unroll
        for (int ks = 0; ks < 8; ++ks) {
            bf16x8 pa = *(const bf16x8*)&Pw[rl * VP + ks * 32 + kc * 8];
            bf16x8 v0 = *(const bf16x8*)&Vt[rl * VP + ks * 32 + kc * 8];
            bf16x8 v1 = *(const bf16x8*)&Vt[(16 + rl) * VP + ks * 32 + kc * 8];
            o0 = __builtin_amdgcn_mfma_f32_16x16x32_bf16(pa, v0, o0, 0, 0, 0);
            o1 = __builtin_amdgcn_mfma_f32_16x16x32_bf16(pa, v1, o1, 0, 0, 0);
        }
#pragma unroll
        for (int j = 0; j < 4; ++j) {
            float sj = __shfl(sumv, kc * 4 + j);
            float inv = 1.f / sj;
            int q = w * 64 + m * 16 + kc * 4 + j;
            unsigned short* orow = o + ((size_t)b * NNODE + q) * OSTR + OOFF + h * DHEAD;
            orow[rl]      = f2b(o0[j] * inv);
            orow[16 + rl] = f2b(o1[j] * inv);
        }
    }
}

// ---------------------------------------------------------------------------
extern "C" void kernel_launch(void* const* d_in, const int* in_sizes, int n_in,
                              void* d_out, int out_size, void* d_ws, size_t ws_size,
                              hipStream_t stream) {
    const float* x          = (const float*)d_in[0];
    const float* edge_attr  = (const float*)d_in[1];
    const float* node_w     = (const float*)d_in[2];
    const float* node_b     = (const float*)d_in[3];
    const float* edge_w     = (const float*)d_in[4];
    const float* edge_b     = (const float*)d_in[5];
    const float* gine_w1    = (const float*)d_in[6];
    const float* gine_b1    = (const float*)d_in[7];
    const float* gine_w2    = (const float*)d_in[8];
    const float* gine_b2    = (const float*)d_in[9];
    const float* attn_in_w  = (const float*)d_in[10];
    const float* attn_in_b  = (const float*)d_in[11];
    const float* attn_out_w = (const float*)d_in[12];
    const float* attn_out_b = (const float*)d_in[13];
    const float* mlp_w1     = (const float*)d_in[14];
    const float* mlp_b1     = (const float*)d_in[15];
    const float* mlp_w2     = (const float*)d_in[16];
    const float* mlp_b2     = (const float*)d_in[17];
    const float* bn1_g      = (const float*)d_in[18];
    const float* bn1_b      = (const float*)d_in[19];
    const float* bn2_g      = (const float*)d_in[20];
    const float* bn2_b      = (const float*)d_in[21];
    const float* bn3_g      = (const float*)d_in[22];
    const float* bn3_b      = (const float*)d_in[23];
    const int*   edge_index = (const int*)d_in[24];

    const int* srcp = edge_index;
    const int* dstp = edge_index + EDGES;

    float* out = (float*)d_out;
    char*  ws  = (char*)d_ws;

    // ---- workspace layout (all activations bf16) ----
    size_t off = 0;
    unsigned short* hb    = (unsigned short*)(ws + off); off += (size_t)NTOT * DMODEL * 2;
    unsigned short* comb2 = (unsigned short*)(ws + off); off += (size_t)NTOT * 512 * 2;   // [hid | o]
    unsigned short* qkvb  = (unsigned short*)(ws + off); off += (size_t)NTOT * 768 * 2;
    unsigned short* zb    = (unsigned short*)(ws + off); off += (size_t)NTOT * DMODEL * 2;
    unsigned short* cmbb  = (unsigned short*)(ws + off); off += (size_t)NTOT * DMODEL * 2;
    unsigned short* h5b   = (unsigned short*)(ws + off); off += (size_t)NTOT * 512 * 2;
    unsigned short* xb    = (unsigned short*)(ws + off); off += (size_t)NTOT * DIN * 2;
    unsigned short* w_node = (unsigned short*)(ws + off); off += (size_t)DMODEL * DIN * 2;
    unsigned short* w_g1   = (unsigned short*)(ws + off); off += (size_t)NLAYER * DMODEL * DMODEL * 2;
    unsigned short* w_cat  = (unsigned short*)(ws + off); off += (size_t)NLAYER * DMODEL * 512 * 2;  // [g2*s1 ; ao*s2]
    unsigned short* w_ai   = (unsigned short*)(ws + off); off += (size_t)NLAYER * 3 * DMODEL * DMODEL * 2;
    unsigned short* w_m1   = (unsigned short*)(ws + off); off += (size_t)NLAYER * 2 * DMODEL * DMODEL * 2;
    unsigned short* w_m2s  = (unsigned short*)(ws + off); off += (size_t)NLAYER * DMODEL * 512 * 2;  // m2*s3
    float* biasC = (float*)(ws + off); off += (size_t)NLAYER * DMODEL * 4;
    float* rC    = (float*)(ws + off); off += (size_t)NLAYER * DMODEL * 4;
    float* biasF = (float*)(ws + off); off += (size_t)NLAYER * DMODEL * 4;
    float* rF    = (float*)(ws + off); off += (size_t)NLAYER * DMODEL * 4;
    int*   rowptr = (int*)(ws + off);   off += ((size_t)NTOT + 4) * 4;
    int*   sp     = (int*)(ws + off);   off += (size_t)EDGES * 4;
    float* eap    = (float*)(ws + off); off += (size_t)EDGES * 4;
    int*   cnt    = (int*)(ws + off);   off += (size_t)NTOT * 4;
    int*   bsum   = (int*)(ws + off);   off += 128 * 4;
    (void)ws_size; (void)in_sizes; (void)n_in; (void)out_size;

    // ---- CSR build ----
    hipMemsetAsync(cnt, 0, (size_t)NTOT * 4, stream);
    k_hist<<<EDGES / 256, 256, 0, stream>>>(dstp, cnt);
    k_block_sum<<<NTOT / 256, 256, 0, stream>>>(cnt, bsum);
    k_scan_bsum<<<1, 64, 0, stream>>>(bsum, NTOT / 256);
    k_scan_chunks<<<NTOT / 256, 256, 0, stream>>>(cnt, bsum, rowptr);
    hipMemsetAsync(cnt, 0, (size_t)NTOT * 4, stream);
    k_fill_csr<<<EDGES / 256, 256, 0, stream>>>(srcp, dstp, edge_attr, rowptr, cnt, sp, eap);

    // ---- weight & input conversion (BN scales folded into weights) ----
    k_f2b<<<NTOT * DIN / 4 / 256, 256, 0, stream>>>(x, xb, NTOT * DIN);
    k_convT<<<dim3(8, 2, 1), 256, 0, stream>>>(node_w, w_node, DIN, DMODEL, nullptr, DIN, 0);
    k_convT<<<dim3(8, 8, NLAYER), 256, 0, stream>>>(gine_w1, w_g1, DMODEL, DMODEL, nullptr, DMODEL, 0);
    k_convT<<<dim3(8, 8, NLAYER), 256, 0, stream>>>(gine_w2, w_cat, DMODEL, DMODEL, bn1_g, 512, 0);
    k_convT<<<dim3(8, 8, NLAYER), 256, 0, stream>>>(attn_out_w, w_cat, DMODEL, DMODEL, bn2_g, 512, 256);
    k_convT<<<dim3(24, 8, NLAYER), 256, 0, stream>>>(attn_in_w, w_ai, DMODEL, 3 * DMODEL, nullptr, DMODEL, 0);
    k_convT<<<dim3(16, 8, NLAYER), 256, 0, stream>>>(mlp_w1, w_m1, DMODEL, 2 * DMODEL, nullptr, DMODEL, 0);
    k_convT<<<dim3(8, 16, NLAYER), 256, 0, stream>>>(mlp_w2, w_m2s, 2 * DMODEL, DMODEL, bn3_g, 512, 0);
    k_mkvec<<<NLAYER, 256, 0, stream>>>(bn1_g, bn1_b, bn2_g, bn2_b, bn3_g, bn3_b,
                                        gine_b2, attn_out_b, mlp_b2, biasC, rC, biasF, rF);

    // ---- encoder: hb = bf16(x @ node_w + node_b) ----
    k_mm<0><<<dim3(2, NTOT / 128), 256, 0, stream>>>(
        xb, w_node, node_b, nullptr, nullptr, nullptr, hb, NTOT, DMODEL, DIN, DMODEL);

    for (int l = 0; l < NLAYER; ++l) {
        const unsigned short* g1 = w_g1 + (size_t)l * DMODEL * DMODEL;
        const unsigned short* wc = w_cat + (size_t)l * DMODEL * 512;
        const unsigned short* ai = w_ai + (size_t)l * 3 * DMODEL * DMODEL;
        const unsigned short* m1 = w_m1 + (size_t)l * 2 * DMODEL * DMODEL;
        const unsigned short* m2 = w_m2s + (size_t)l * DMODEL * 512;

        // GINE aggregate -> zb (bf16)
        k_gine_agg<<<BGRAPH * 2, 1024, 0, stream>>>(hb, rowptr, sp, eap,
                                                    edge_w, edge_b, zb);
        // hid = relu(z @ w1 + b1) -> comb2[:, 0:256]  (ldc = 512)
        k_mm<1><<<dim3(2, NTOT / 128), 256, 0, stream>>>(
            zb, g1, gine_b1 + (size_t)l * DMODEL, nullptr, nullptr, nullptr,
            comb2, NTOT, DMODEL, DMODEL, 512);
        // qkv = h @ attn_in_w + b -> qkvb
        k_mm<0><<<dim3(6, NTOT / 128), 256, 0, stream>>>(
            hb, ai, attn_in_b + (size_t)l * 3 * DMODEL, nullptr, nullptr, nullptr,
            qkvb, NTOT, 3 * DMODEL, DMODEL, 3 * DMODEL);
        // attention -> comb2[:, 256:512]
        k_attn<<<BGRAPH * NHEAD, 256, 0, stream>>>(qkvb, comb2);
        // comb = [hid|o] @ [g2*s1; ao*s2] + biasC + rC*h  -> cmbb
        k_mm<4><<<dim3(2, NTOT / 128), 256, 0, stream>>>(
            comb2, wc, biasC + (size_t)l * DMODEL, rC + (size_t)l * DMODEL, hb,
            nullptr, cmbb, NTOT, DMODEL, 512, DMODEL);
        // h5 = relu(comb @ mlp_w1 + b1) -> h5b
        k_mm<1><<<dim3(4, NTOT / 128), 256, 0, stream>>>(
            cmbb, m1, mlp_b1 + (size_t)l * 2 * DMODEL, nullptr, nullptr, nullptr,
            h5b, NTOT, 2 * DMODEL, DMODEL, 2 * DMODEL);
        // h = h5 @ (m2*s3) + biasF + rF*comb -> hb (+ fp32 out on last layer)
        float* dest = (l == NLAYER - 1) ? out : nullptr;
        k_mm<4><<<dim3(2, NTOT / 128), 256, 0, stream>>>(
            h5b, m2, biasF + (size_t)l * DMODEL, rF + (size_t)l * DMODEL, cmbb,
            dest, hb, NTOT, DMODEL, 512, DMODEL);
    }
}

// Round 7
// 996.774 us; speedup vs baseline: 1.3123x; 1.1541x over previous
//
#include <hip/hip_runtime.h>
#include <math.h>

#define NTOT   32768
#define DMODEL 256
#define EDGES  1048576
#define BGRAPH 128
#define NNODE  256
#define NHEAD  8
#define DHEAD  32
#define NLAYER 4
#define DIN    64
#define BNS    0.9999950000374997f   // 1/sqrt(1+1e-5)
#define CAPG   9216                   // per-graph edge bucket capacity (mean 8192, sigma ~90)

typedef short bf16x8 __attribute__((ext_vector_type(8)));
typedef float f32x4  __attribute__((ext_vector_type(4)));

__device__ __forceinline__ unsigned short f2b(float f) {
    union { float f; unsigned int u; } v; v.f = f;
    unsigned int r = v.u + 0x7FFFu + ((v.u >> 16) & 1u);  // RNE
    return (unsigned short)(r >> 16);
}
__device__ __forceinline__ float b2f(unsigned short u) {
    union { unsigned int u; float f; } v; v.u = ((unsigned int)u) << 16;
    return v.f;
}

// ---------------------------------------------------------------------------
// Pass 1: bucket edges by graph. 256 blocks x 1024 thr, 4 edges/thr.
// Record: {src_local | dst_local<<16, ea_bits} (8 B). Buckets are contiguous
// per graph -> scatter targets 128 hot regions (L2-friendly, ~10 MB writes).
// ---------------------------------------------------------------------------
__global__ __launch_bounds__(1024)
void k_bucket(const int* __restrict__ src, const int* __restrict__ dst,
              const float* __restrict__ ea, int* __restrict__ gcnt,
              uint2* __restrict__ gbuf) {
    __shared__ int hist[BGRAPH], base[BGRAPH], cur[BGRAPH];
    int t = threadIdx.x;
    int e0 = blockIdx.x * 4096;
    if (t < BGRAPH) { hist[t] = 0; cur[t] = 0; }
    __syncthreads();
    int g4[4]; unsigned int m4[4], a4[4];
#pragma unroll
    for (int j = 0; j < 4; ++j) {
        int e = e0 + j * 1024 + t;
        int s = src[e], d = dst[e];
        g4[j] = d >> 8;
        m4[j] = (unsigned int)(s & 255) | ((unsigned int)(d & 255) << 16);
        a4[j] = __float_as_uint(ea[e]);
        atomicAdd(&hist[g4[j]], 1);
    }
    __syncthreads();
    if (t < BGRAPH) base[t] = atomicAdd(&gcnt[t], hist[t]);
    __syncthreads();
#pragma unroll
    for (int j = 0; j < 4; ++j) {
        int g = g4[j];
        int slot = base[g] + atomicAdd(&cur[g], 1);
        if (slot < CAPG) {
            uint2 r; r.x = m4[j]; r.y = a4[j];
            gbuf[(size_t)g * CAPG + slot] = r;
        }
    }
}

// ---------------------------------------------------------------------------
// Pass 2: per-graph counting sort by dst (in LDS) -> CSR records + rowptr.
// 1 block/graph, 1024 thr. All reads/writes block-contiguous (~72 KB/graph).
// rowptr layout: [g][257] absolute offsets into epk.
// ---------------------------------------------------------------------------
__global__ __launch_bounds__(1024)
void k_gsort(const uint2* __restrict__ gbuf, const int* __restrict__ gcnt,
             uint2* __restrict__ epk, int* __restrict__ rowptr) {
    __shared__ int s[NNODE], excl[NNODE + 1], cur[NNODE];
    int g = blockIdx.x;
    int c = gcnt[g];
    int t = threadIdx.x;
    size_t base = (size_t)g * CAPG;
    if (t < NNODE) { s[t] = 0; cur[t] = 0; }
    __syncthreads();
    for (int i = t; i < c; i += 1024)
        atomicAdd(&s[gbuf[base + i].x >> 16], 1);
    __syncthreads();
    // Hillis-Steele inclusive scan over s[0..255]
    for (int o = 1; o < NNODE; o <<= 1) {
        int add = (t < NNODE && t >= o) ? s[t - o] : 0;
        __syncthreads();
        if (t < NNODE) s[t] += add;
        __syncthreads();
    }
    if (t < NNODE) excl[t + 1] = s[t];
    if (t == 0) excl[0] = 0;
    __syncthreads();
    if (t <= NNODE) rowptr[g * (NNODE + 1) + t] = (int)base + excl[t];
    for (int i = t; i < c; i += 1024) {
        uint2 r = gbuf[base + i];
        int dl = r.x >> 16;
        int p = excl[dl] + atomicAdd(&cur[dl], 1);
        epk[base + p] = r;
    }
}

// ---------------------------------------------------------------------------
// fp32 -> bf16 elementwise (n % 4 == 0)
// ---------------------------------------------------------------------------
__global__ void k_f2b(const float* __restrict__ s, unsigned short* __restrict__ d, int n) {
    int i = (blockIdx.x * 256 + threadIdx.x) * 4;
    if (i >= n) return;
    float4 v = *(const float4*)(s + i);
    d[i + 0] = f2b(v.x); d[i + 1] = f2b(v.y); d[i + 2] = f2b(v.z); d[i + 3] = f2b(v.w);
}

// ---------------------------------------------------------------------------
// Weight convert + transpose (+optional per-output-col BN scale fold):
// src[l][k][n] fp32 -> dst[l][n][koff + k] bf16, dst row stride Kdst.
// ---------------------------------------------------------------------------
__global__ __launch_bounds__(256)
void k_convT(const float* __restrict__ src, unsigned short* __restrict__ dst, int K_, int N_,
             const float* __restrict__ scale, int Kdst, int koff) {
    __shared__ float tile[32][33];
    int l = blockIdx.z;
    int n0 = blockIdx.x * 32, k0 = blockIdx.y * 32;
    const float* s = src + (size_t)l * K_ * N_;
    unsigned short* d = dst + (size_t)l * N_ * Kdst;
    int tx = threadIdx.x & 31, ty = threadIdx.x >> 5;
#pragma unroll
    for (int i = 0; i < 32; i += 8)
        tile[ty + i][tx] = s[(size_t)(k0 + ty + i) * N_ + n0 + tx];
    __syncthreads();
#pragma unroll
    for (int i = 0; i < 32; i += 8) {
        int n = n0 + ty + i;
        float sc = scale ? scale[(size_t)l * N_ + n] * BNS : 1.f;
        d[(size_t)n * Kdst + koff + k0 + tx] = f2b(tile[tx][ty + i] * sc);
    }
}

// ---------------------------------------------------------------------------
// Per-layer fused epilogue vectors
// ---------------------------------------------------------------------------
__global__ void k_mkvec(const float* __restrict__ bn1_g, const float* __restrict__ bn1_b,
                        const float* __restrict__ bn2_g, const float* __restrict__ bn2_b,
                        const float* __restrict__ bn3_g, const float* __restrict__ bn3_b,
                        const float* __restrict__ gb2, const float* __restrict__ aob,
                        const float* __restrict__ mb2,
                        float* __restrict__ biasC, float* __restrict__ rC,
                        float* __restrict__ biasF, float* __restrict__ rF) {
    int i = blockIdx.x * 256 + threadIdx.x;
    float s1 = bn1_g[i] * BNS, t1 = bn1_b[i];
    float s2 = bn2_g[i] * BNS, t2 = bn2_b[i];
    float s3 = bn3_g[i] * BNS, t3 = bn3_b[i];
    biasC[i] = gb2[i] * s1 + t1 + aob[i] * s2 + t2;
    rC[i]    = s1 + s2;
    biasF[i] = mb2[i] * s3 + t3;
    rF[i]    = s3;
}

// ---------------------------------------------------------------------------
// GINE aggregation, graph-local LDS gather, 1024 threads (16 waves).
// 2 blocks/graph; each stages the full graph h (128 KB) and owns 128 dst nodes.
// CSR records epk = {src_local, ea_bits}, rowptr[g][257] absolute.
// ---------------------------------------------------------------------------
__global__ __launch_bounds__(1024)
void k_gine_agg(const unsigned short* __restrict__ hb,
                const int* __restrict__ rowptr,
                const uint2* __restrict__ epk,
                const float* __restrict__ ew, const float* __restrict__ eb,
                unsigned short* __restrict__ zb) {
    __shared__ unsigned short lds_h[NNODE * DMODEL];   // 128 KB
    int g = blockIdx.x >> 1, half = blockIdx.x & 1;
    int t = threadIdx.x;

    const unsigned short* gsrc = hb + (size_t)g * NNODE * DMODEL;
#pragma unroll
    for (int i = 0; i < 8; ++i) {
        int slot = i * 1024 + t;
        __builtin_amdgcn_global_load_lds(
            (const __attribute__((address_space(1))) void*)(gsrc + slot * 8),
            (__attribute__((address_space(3))) void*)&lds_h[slot * 8], 16, 0, 0);
    }
    asm volatile("s_waitcnt vmcnt(0)" ::: "memory");
    __syncthreads();

    int w = t >> 6, lane = t & 63;
    int d0 = lane * 4;
    float4 ew4 = *(const float4*)&ew[d0];
    float4 eb4 = *(const float4*)&eb[d0];

    const int* rp = rowptr + g * (NNODE + 1);
    int ln0 = half * 128 + w * 8;
    for (int ln = ln0; ln < ln0 + 8; ++ln) {
        int beg = rp[ln], end = rp[ln + 1];
        float a0 = 0.f, a1 = 0.f, a2 = 0.f, a3 = 0.f;
        for (int c = beg; c < end; c += 64) {
            int cnt = min(64, end - c);
            int sl_ = 0, avb_ = 0;
            if (lane < cnt) {
                uint2 r = epk[c + lane];
                sl_  = (int)(r.x & 0xffffu);
                avb_ = (int)r.y;
            }
#pragma unroll 4
            for (int i = 0; i < cnt; ++i) {
                int   sl = __builtin_amdgcn_readlane(sl_, i);
                float av = __int_as_float(__builtin_amdgcn_readlane(avb_, i));
                uint2 hv = *(const uint2*)&lds_h[sl * DMODEL + d0];
                float t0 = fmaf(av, ew4.x, eb4.x);
                float t1 = fmaf(av, ew4.y, eb4.y);
                float t2 = fmaf(av, ew4.z, eb4.z);
                float t3 = fmaf(av, ew4.w, eb4.w);
                a0 += fmaxf(__uint_as_float(hv.x << 16) + t0, 0.f);
                a1 += fmaxf(__uint_as_float(hv.x & 0xffff0000u) + t1, 0.f);
                a2 += fmaxf(__uint_as_float(hv.y << 16) + t2, 0.f);
                a3 += fmaxf(__uint_as_float(hv.y & 0xffff0000u) + t3, 0.f);
            }
        }
        uint2 hv = *(const uint2*)&lds_h[ln * DMODEL + d0];
        float z0 = __uint_as_float(hv.x << 16)         + a0;
        float z1 = __uint_as_float(hv.x & 0xffff0000u) + a1;
        float z2 = __uint_as_float(hv.y << 16)         + a2;
        float z3 = __uint_as_float(hv.y & 0xffff0000u) + a3;
        unsigned int lo, hi;
        asm("v_cvt_pk_bf16_f32 %0, %1, %2" : "=v"(lo) : "v"(z0), "v"(z1));
        asm("v_cvt_pk_bf16_f32 %0, %1, %2" : "=v"(hi) : "v"(z2), "v"(z3));
        uint2 pk; pk.x = lo; pk.y = hi;
        *(uint2*)&zb[((size_t)g * NNODE + ln) * DMODEL + d0] = pk;
    }
}

// ---------------------------------------------------------------------------
// bf16 MFMA GEMM, BK=64 with chunk-XOR swizzle (pre-swizzled global source +
// swizzled ds_read; gload_lds dest stays linear). C[M,N] = A[M,K] @ Bt[N,K]^T.
// MODE 0: +bias   1: relu(+bias)   4: +bias + rvec[col]*res_bf16[row,col]
// ---------------------------------------------------------------------------
template <int MODE>
__global__ __launch_bounds__(256)
void k_mm(const unsigned short* __restrict__ A, const unsigned short* __restrict__ Bt,
          const float* __restrict__ bias, const float* __restrict__ rvec,
          const unsigned short* __restrict__ resb, float* __restrict__ Cf,
          unsigned short* __restrict__ Cb, int M, int N, int K, int ldc) {
    const int BM = 128, BN = 128, BK = 64;
    __shared__ unsigned short As[BM * BK];   // 16 KB
    __shared__ unsigned short Bs[BN * BK];   // 16 KB

    int t = threadIdx.x;
    int w = t >> 6, l = t & 63;
    int wr = w >> 1, wc = w & 1;
    int bm = blockIdx.y * BM, bn = blockIdx.x * BN;

    f32x4 acc[4][4] = {};
    int rl = l & 15, kc = l >> 4;

    for (int k0 = 0; k0 < K; k0 += BK) {
#pragma unroll
        for (int i = 0; i < 4; ++i) {
            int slot = i * 256 + t;                 // physical 16B slot
            int row = slot >> 3, pc = slot & 7;
            int lc = pc ^ (row & 7);                // logical chunk for this slot
            const unsigned short* gp = A + (size_t)(bm + row) * K + k0 + lc * 8;
            __builtin_amdgcn_global_load_lds(
                (const __attribute__((address_space(1))) void*)gp,
                (__attribute__((address_space(3))) void*)&As[(i * 256 + w * 64) * 8],
                16, 0, 0);
        }
#pragma unroll
        for (int i = 0; i < 4; ++i) {
            int slot = i * 256 + t;
            int row = slot >> 3, pc = slot & 7;
            int lc = pc ^ (row & 7);
            const unsigned short* gp = Bt + (size_t)(bn + row) * K + k0 + lc * 8;
            __builtin_amdgcn_global_load_lds(
                (const __attribute__((address_space(1))) void*)gp,
                (__attribute__((address_space(3))) void*)&Bs[(i * 256 + w * 64) * 8],
                16, 0, 0);
        }
        asm volatile("s_waitcnt vmcnt(0)" ::: "memory");
        __syncthreads();

#pragma unroll
        for (int kk = 0; kk < 2; ++kk) {
            int lch = kk * 4 + kc;
            bf16x8 av[4], bv[4];
#pragma unroll
            for (int m = 0; m < 4; ++m) {
                int r = wr * 64 + m * 16 + rl;
                av[m] = *(const bf16x8*)&As[r * BK + ((lch ^ (r & 7)) << 3)];
            }
#pragma unroll
            for (int n = 0; n < 4; ++n) {
                int r = wc * 64 + n * 16 + rl;
                bv[n] = *(const bf16x8*)&Bs[r * BK + ((lch ^ (r & 7)) << 3)];
            }
#pragma unroll
            for (int m = 0; m < 4; ++m)
#pragma unroll
                for (int n = 0; n < 4; ++n)
                    acc[m][n] = __builtin_amdgcn_mfma_f32_16x16x32_bf16(av[m], bv[n], acc[m][n], 0, 0, 0);
        }
        __syncthreads();
    }

    int rh = l >> 4;
#pragma unroll
    for (int n = 0; n < 4; ++n) {
        int col = bn + wc * 64 + n * 16 + rl;
        float bv_ = bias[col];
        float rv = 0.f;
        if (MODE == 4) rv = rvec[col];
#pragma unroll
        for (int m = 0; m < 4; ++m) {
#pragma unroll
            for (int j = 0; j < 4; ++j) {
                int row = bm + wr * 64 + m * 16 + rh * 4 + j;
                size_t idx = (size_t)row * ldc + col;
                float v = acc[m][n][j] + bv_;
                if (MODE == 1) v = fmaxf(v, 0.f);
                if (MODE == 4) v += rv * b2f(resb[idx]);
                if (Cf) Cf[idx] = v;
                Cb[idx] = f2b(v);
            }
        }
    }
}

// ---------------------------------------------------------------------------
// MFMA attention, swapped-operand QK^T. Output into concat buffer [M,512]
// at column offset 256.
// ---------------------------------------------------------------------------
#define KP 40
#define VP 264
#define OSTR 512
#define OOFF 256
__global__ __launch_bounds__(256)
void k_attn(const unsigned short* __restrict__ qkv, unsigned short* __restrict__ o) {
    __shared__ unsigned short lds[10240 + 8448 + 16896]; // Ks | Vt | Ps (71168 B)
    unsigned short* Ks = lds;                 // [256][40]
    unsigned short* Vt = lds + 10240;         // [32][264]
    unsigned short* Ps = lds + 10240 + 8448;  // 4 x [16][264]

    int bh = blockIdx.x;
    int b = bh >> 3, h = bh & 7;
    int t = threadIdx.x;
    int w = t >> 6, l = t & 63;
    int rl = l & 15, kc = l >> 4;
    const float scale = 0.17677669529663687f; // 1/sqrt(32)

    const unsigned short* base = qkv + (size_t)b * NNODE * (3 * DMODEL);

    {
        const unsigned short* row = base + (size_t)t * (3 * DMODEL);
#pragma unroll
        for (int c = 0; c < 4; ++c) {
            bf16x8 kvv = *(const bf16x8*)(row + DMODEL + h * DHEAD + c * 8);
            *(bf16x8*)&Ks[t * KP + c * 8] = kvv;
        }
    }
    {
        int k0 = (t & 63) * 4, d0 = (t >> 6) * 8;
        bf16x8 vr[4];
#pragma unroll
        for (int i = 0; i < 4; ++i)
            vr[i] = *(const bf16x8*)(base + (size_t)(k0 + i) * (3 * DMODEL) + 2 * DMODEL + h * DHEAD + d0);
#pragma unroll
        for (int d = 0; d < 8; ++d) {
            ushort4 pk;
            pk.x = (unsigned short)vr[0][d];
            pk.y = (unsigned short)vr[1][d];
            pk.z = (unsigned short)vr[2][d];
            pk.w = (unsigned short)vr[3][d];
            *(ushort4*)&Vt[(d0 + d) * VP + k0] = pk;
        }
    }

    bf16x8 qv[4];
#pragma unroll
    for (int m = 0; m < 4; ++m) {
        int q = w * 64 + m * 16 + rl;
        qv[m] = *(const bf16x8*)(base + (size_t)q * (3 * DMODEL) + h * DHEAD + kc * 8);
    }
    __syncthreads();

    unsigned short* Pw = Ps + w * 16 * VP;
    f32x4 zero = {0.f, 0.f, 0.f, 0.f};

#pragma unroll 1
    for (int m = 0; m < 4; ++m) {
        f32x4 s[16];
#pragma unroll
        for (int n = 0; n < 16; ++n) {
            bf16x8 kv = *(const bf16x8*)&Ks[(n * 16 + rl) * KP + kc * 8];
            s[n] = __builtin_amdgcn_mfma_f32_16x16x32_bf16(kv, qv[m], zero, 0, 0, 0);
        }
        float mv = -1e30f;
#pragma unroll
        for (int n = 0; n < 16; ++n)
#pragma unroll
            for (int j = 0; j < 4; ++j) mv = fmaxf(mv, s[n][j]);
        mv = fmaxf(mv, __shfl_xor(mv, 16));
        mv = fmaxf(mv, __shfl_xor(mv, 32));
        float sumv = 0.f;
#pragma unroll
        for (int n = 0; n < 16; ++n) {
            float p0 = __expf((s[n][0] - mv) * scale);
            float p1 = __expf((s[n][1] - mv) * scale);
            float p2 = __expf((s[n][2] - mv) * scale);
            float p3 = __expf((s[n][3] - mv) * scale);
            sumv += (p0 + p1) + (p2 + p3);
            unsigned int lo, hi;
            asm("v_cvt_pk_bf16_f32 %0, %1, %2" : "=v"(lo) : "v"(p0), "v"(p1));
            asm("v_cvt_pk_bf16_f32 %0, %1, %2" : "=v"(hi) : "v"(p2), "v"(p3));
            uint2 pk; pk.x = lo; pk.y = hi;
            *(uint2*)&Pw[rl * VP + n * 16 + kc * 4] = pk;
        }
        sumv += __shfl_xor(sumv, 16);
        sumv += __shfl_xor(sumv, 32);

        f32x4 o0 = zero, o1 = zero;
#pragma unroll
        for (int ks = 0; ks < 8; ++ks) {
            bf16x8 pa = *(const bf16x8*)&Pw[rl * VP + ks * 32 + kc * 8];
            bf16x8 v0 = *(const bf16x8*)&Vt[rl * VP + ks * 32 + kc * 8];
            bf16x8 v1 = *(const bf16x8*)&Vt[(16 + rl) * VP + ks * 32 + kc * 8];
            o0 = __builtin_amdgcn_mfma_f32_16x16x32_bf16(pa, v0, o0, 0, 0, 0);
            o1 = __builtin_amdgcn_mfma_f32_16x16x32_bf16(pa, v1, o1, 0, 0, 0);
        }
#pragma unroll
        for (int j = 0; j < 4; ++j) {
            float sj = __shfl(sumv, kc * 4 + j);
            float inv = 1.f / sj;
            int q = w * 64 + m * 16 + kc * 4 + j;
            unsigned short* orow = o + ((size_t)b * NNODE + q) * OSTR + OOFF + h * DHEAD;
            orow[rl]      = f2b(o0[j] * inv);
            orow[16 + rl] = f2b(o1[j] * inv);
        }
    }
}

// ---------------------------------------------------------------------------
extern "C" void kernel_launch(void* const* d_in, const int* in_sizes, int n_in,
                              void* d_out, int out_size, void* d_ws, size_t ws_size,
                              hipStream_t stream) {
    const float* x          = (const float*)d_in[0];
    const float* edge_attr  = (const float*)d_in[1];
    const float* node_w     = (const float*)d_in[2];
    const float* node_b     = (const float*)d_in[3];
    const float* edge_w     = (const float*)d_in[4];
    const float* edge_b     = (const float*)d_in[5];
    const float* gine_w1    = (const float*)d_in[6];
    const float* gine_b1    = (const float*)d_in[7];
    const float* gine_w2    = (const float*)d_in[8];
    const float* gine_b2    = (const float*)d_in[9];
    const float* attn_in_w  = (const float*)d_in[10];
    const float* attn_in_b  = (const float*)d_in[11];
    const float* attn_out_w = (const float*)d_in[12];
    const float* attn_out_b = (const float*)d_in[13];
    const float* mlp_w1     = (const float*)d_in[14];
    const float* mlp_b1     = (const float*)d_in[15];
    const float* mlp_w2     = (const float*)d_in[16];
    const float* mlp_b2     = (const float*)d_in[17];
    const float* bn1_g      = (const float*)d_in[18];
    const float* bn1_b      = (const float*)d_in[19];
    const float* bn2_g      = (const float*)d_in[20];
    const float* bn2_b      = (const float*)d_in[21];
    const float* bn3_g      = (const float*)d_in[22];
    const float* bn3_b      = (const float*)d_in[23];
    const int*   edge_index = (const int*)d_in[24];

    const int* srcp = edge_index;
    const int* dstp = edge_index + EDGES;

    float* out = (float*)d_out;
    char*  ws  = (char*)d_ws;

    // ---- workspace layout ----
    size_t off = 0;
    unsigned short* hb    = (unsigned short*)(ws + off); off += (size_t)NTOT * DMODEL * 2;
    unsigned short* comb2 = (unsigned short*)(ws + off); off += (size_t)NTOT * 512 * 2;   // [hid | o]
    unsigned short* qkvb  = (unsigned short*)(ws + off); off += (size_t)NTOT * 768 * 2;
    unsigned short* zb    = (unsigned short*)(ws + off); off += (size_t)NTOT * DMODEL * 2;
    unsigned short* cmbb  = (unsigned short*)(ws + off); off += (size_t)NTOT * DMODEL * 2;
    unsigned short* h5b   = (unsigned short*)(ws + off); off += (size_t)NTOT * 512 * 2;
    unsigned short* xb    = (unsigned short*)(ws + off); off += (size_t)NTOT * DIN * 2;
    unsigned short* w_node = (unsigned short*)(ws + off); off += (size_t)DMODEL * DIN * 2;
    unsigned short* w_g1   = (unsigned short*)(ws + off); off += (size_t)NLAYER * DMODEL * DMODEL * 2;
    unsigned short* w_cat  = (unsigned short*)(ws + off); off += (size_t)NLAYER * DMODEL * 512 * 2;  // [g2*s1 ; ao*s2]
    unsigned short* w_ai   = (unsigned short*)(ws + off); off += (size_t)NLAYER * 3 * DMODEL * DMODEL * 2;
    unsigned short* w_m1   = (unsigned short*)(ws + off); off += (size_t)NLAYER * 2 * DMODEL * DMODEL * 2;
    unsigned short* w_m2s  = (unsigned short*)(ws + off); off += (size_t)NLAYER * DMODEL * 512 * 2;  // m2*s3
    float* biasC = (float*)(ws + off); off += (size_t)NLAYER * DMODEL * 4;
    float* rC    = (float*)(ws + off); off += (size_t)NLAYER * DMODEL * 4;
    float* biasF = (float*)(ws + off); off += (size_t)NLAYER * DMODEL * 4;
    float* rF    = (float*)(ws + off); off += (size_t)NLAYER * DMODEL * 4;
    uint2* gbuf  = (uint2*)(ws + off);  off += (size_t)BGRAPH * CAPG * 8;
    uint2* epk   = (uint2*)(ws + off);  off += (size_t)BGRAPH * CAPG * 8;
    int*   gcnt  = (int*)(ws + off);    off += (size_t)BGRAPH * 4;
    int*   rowptr = (int*)(ws + off);   off += (size_t)BGRAPH * (NNODE + 1) * 4;
    (void)ws_size; (void)in_sizes; (void)n_in; (void)out_size;

    // ---- CSR build (bucket by graph, then per-graph LDS counting sort) ----
    hipMemsetAsync(gcnt, 0, (size_t)BGRAPH * 4, stream);
    k_bucket<<<EDGES / 4096, 1024, 0, stream>>>(srcp, dstp, edge_attr, gcnt, gbuf);
    k_gsort<<<BGRAPH, 1024, 0, stream>>>(gbuf, gcnt, epk, rowptr);

    // ---- weight & input conversion (BN scales folded into weights) ----
    k_f2b<<<NTOT * DIN / 4 / 256, 256, 0, stream>>>(x, xb, NTOT * DIN);
    k_convT<<<dim3(8, 2, 1), 256, 0, stream>>>(node_w, w_node, DIN, DMODEL, nullptr, DIN, 0);
    k_convT<<<dim3(8, 8, NLAYER), 256, 0, stream>>>(gine_w1, w_g1, DMODEL, DMODEL, nullptr, DMODEL, 0);
    k_convT<<<dim3(8, 8, NLAYER), 256, 0, stream>>>(gine_w2, w_cat, DMODEL, DMODEL, bn1_g, 512, 0);
    k_convT<<<dim3(8, 8, NLAYER), 256, 0, stream>>>(attn_out_w, w_cat, DMODEL, DMODEL, bn2_g, 512, 256);
    k_convT<<<dim3(24, 8, NLAYER), 256, 0, stream>>>(attn_in_w, w_ai, DMODEL, 3 * DMODEL, nullptr, DMODEL, 0);
    k_convT<<<dim3(16, 8, NLAYER), 256, 0, stream>>>(mlp_w1, w_m1, DMODEL, 2 * DMODEL, nullptr, DMODEL, 0);
    k_convT<<<dim3(8, 16, NLAYER), 256, 0, stream>>>(mlp_w2, w_m2s, 2 * DMODEL, DMODEL, bn3_g, 512, 0);
    k_mkvec<<<NLAYER, 256, 0, stream>>>(bn1_g, bn1_b, bn2_g, bn2_b, bn3_g, bn3_b,
                                        gine_b2, attn_out_b, mlp_b2, biasC, rC, biasF, rF);

    // ---- encoder: hb = bf16(x @ node_w + node_b) ----
    k_mm<0><<<dim3(2, NTOT / 128), 256, 0, stream>>>(
        xb, w_node, node_b, nullptr, nullptr, nullptr, hb, NTOT, DMODEL, DIN, DMODEL);

    for (int l = 0; l < NLAYER; ++l) {
        const unsigned short* g1 = w_g1 + (size_t)l * DMODEL * DMODEL;
        const unsigned short* wc = w_cat + (size_t)l * DMODEL * 512;
        const unsigned short* ai = w_ai + (size_t)l * 3 * DMODEL * DMODEL;
        const unsigned short* m1 = w_m1 + (size_t)l * 2 * DMODEL * DMODEL;
        const unsigned short* m2 = w_m2s + (size_t)l * DMODEL * 512;

        // GINE aggregate -> zb (bf16)
        k_gine_agg<<<BGRAPH * 2, 1024, 0, stream>>>(hb, rowptr, epk, edge_w, edge_b, zb);
        // hid = relu(z @ w1 + b1) -> comb2[:, 0:256]  (ldc = 512)
        k_mm<1><<<dim3(2, NTOT / 128), 256, 0, stream>>>(
            zb, g1, gine_b1 + (size_t)l * DMODEL, nullptr, nullptr, nullptr,
            comb2, NTOT, DMODEL, DMODEL, 512);
        // qkv = h @ attn_in_w + b -> qkvb
        k_mm<0><<<dim3(6, NTOT / 128), 256, 0, stream>>>(
            hb, ai, attn_in_b + (size_t)l * 3 * DMODEL, nullptr, nullptr, nullptr,
            qkvb, NTOT, 3 * DMODEL, DMODEL, 3 * DMODEL);
        // attention -> comb2[:, 256:512]
        k_attn<<<BGRAPH * NHEAD, 256, 0, stream>>>(qkvb, comb2);
        // comb = [hid|o] @ [g2*s1; ao*s2] + biasC + rC*h  -> cmbb
        k_mm<4><<<dim3(2, NTOT / 128), 256, 0, stream>>>(
            comb2, wc, biasC + (size_t)l * DMODEL, rC + (size_t)l * DMODEL, hb,
            nullptr, cmbb, NTOT, DMODEL, 512, DMODEL);
        // h5 = relu(comb @ mlp_w1 + b1) -> h5b
        k_mm<1><<<dim3(4, NTOT / 128), 256, 0, stream>>>(
            cmbb, m1, mlp_b1 + (size_t)l * 2 * DMODEL, nullptr, nullptr, nullptr,
            h5b, NTOT, 2 * DMODEL, DMODEL, 2 * DMODEL);
        // h = h5 @ (m2*s3) + biasF + rF*comb -> hb (+ fp32 out on last layer)
        float* dest = (l == NLAYER - 1) ? out : nullptr;
        k_mm<4><<<dim3(2, NTOT / 128), 256, 0, stream>>>(
            h5b, m2, biasF + (size_t)l * DMODEL, rF + (size_t)l * DMODEL, cmbb,
            dest, hb, NTOT, DMODEL, 512, DMODEL);
    }
}

// Round 8
// 955.395 us; speedup vs baseline: 1.3692x; 1.0433x over previous
//
#include <hip/hip_runtime.h>
#include <math.h>

#define NTOT   32768
#define DMODEL 256
#define EDGES  1048576
#define BGRAPH 128
#define NNODE  256
#define NHEAD  8
#define DHEAD  32
#define NLAYER 4
#define DIN    64
#define BNS    0.9999950000374997f   // 1/sqrt(1+1e-5)
#define CAPG   9216                   // per-graph edge bucket capacity

typedef short bf16x8 __attribute__((ext_vector_type(8)));
typedef float f32x4  __attribute__((ext_vector_type(4)));

__device__ __forceinline__ unsigned short f2b(float f) {
    union { float f; unsigned int u; } v; v.f = f;
    unsigned int r = v.u + 0x7FFFu + ((v.u >> 16) & 1u);  // RNE
    return (unsigned short)(r >> 16);
}
__device__ __forceinline__ float b2f(unsigned short u) {
    union { unsigned int u; float f; } v; v.u = ((unsigned int)u) << 16;
    return v.f;
}

// ---------------------------------------------------------------------------
// Pass 1: bucket edges by graph (L2-friendly coarse scatter).
// ---------------------------------------------------------------------------
__global__ __launch_bounds__(1024)
void k_bucket(const int* __restrict__ src, const int* __restrict__ dst,
              const float* __restrict__ ea, int* __restrict__ gcnt,
              uint2* __restrict__ gbuf) {
    __shared__ int hist[BGRAPH], base[BGRAPH], cur[BGRAPH];
    int t = threadIdx.x;
    int e0 = blockIdx.x * 4096;
    if (t < BGRAPH) { hist[t] = 0; cur[t] = 0; }
    __syncthreads();
    int g4[4]; unsigned int m4[4], a4[4];
#pragma unroll
    for (int j = 0; j < 4; ++j) {
        int e = e0 + j * 1024 + t;
        int s = src[e], d = dst[e];
        g4[j] = d >> 8;
        m4[j] = (unsigned int)(s & 255) | ((unsigned int)(d & 255) << 16);
        a4[j] = __float_as_uint(ea[e]);
        atomicAdd(&hist[g4[j]], 1);
    }
    __syncthreads();
    if (t < BGRAPH) base[t] = atomicAdd(&gcnt[t], hist[t]);
    __syncthreads();
#pragma unroll
    for (int j = 0; j < 4; ++j) {
        int g = g4[j];
        int slot = base[g] + atomicAdd(&cur[g], 1);
        if (slot < CAPG) {
            uint2 r; r.x = m4[j]; r.y = a4[j];
            gbuf[(size_t)g * CAPG + slot] = r;
        }
    }
}

// ---------------------------------------------------------------------------
// Pass 2: per-graph LDS counting sort -> CSR records + rowptr.
// ---------------------------------------------------------------------------
__global__ __launch_bounds__(1024)
void k_gsort(const uint2* __restrict__ gbuf, const int* __restrict__ gcnt,
             uint2* __restrict__ epk, int* __restrict__ rowptr) {
    __shared__ int s[NNODE], excl[NNODE + 1], cur[NNODE];
    int g = blockIdx.x;
    int c = gcnt[g];
    int t = threadIdx.x;
    size_t base = (size_t)g * CAPG;
    if (t < NNODE) { s[t] = 0; cur[t] = 0; }
    __syncthreads();
    for (int i = t; i < c; i += 1024)
        atomicAdd(&s[gbuf[base + i].x >> 16], 1);
    __syncthreads();
    for (int o = 1; o < NNODE; o <<= 1) {
        int add = (t < NNODE && t >= o) ? s[t - o] : 0;
        __syncthreads();
        if (t < NNODE) s[t] += add;
        __syncthreads();
    }
    if (t < NNODE) excl[t + 1] = s[t];
    if (t == 0) excl[0] = 0;
    __syncthreads();
    if (t <= NNODE) rowptr[g * (NNODE + 1) + t] = (int)base + excl[t];
    for (int i = t; i < c; i += 1024) {
        uint2 r = gbuf[base + i];
        int dl = r.x >> 16;
        int p = excl[dl] + atomicAdd(&cur[dl], 1);
        epk[base + p] = r;
    }
}

// ---------------------------------------------------------------------------
__global__ void k_f2b(const float* __restrict__ s, unsigned short* __restrict__ d, int n) {
    int i = (blockIdx.x * 256 + threadIdx.x) * 4;
    if (i >= n) return;
    float4 v = *(const float4*)(s + i);
    d[i + 0] = f2b(v.x); d[i + 1] = f2b(v.y); d[i + 2] = f2b(v.z); d[i + 3] = f2b(v.w);
}

// ---------------------------------------------------------------------------
// Weight convert + transpose (+optional BN scale fold)
// ---------------------------------------------------------------------------
__global__ __launch_bounds__(256)
void k_convT(const float* __restrict__ src, unsigned short* __restrict__ dst, int K_, int N_,
             const float* __restrict__ scale, int Kdst, int koff) {
    __shared__ float tile[32][33];
    int l = blockIdx.z;
    int n0 = blockIdx.x * 32, k0 = blockIdx.y * 32;
    const float* s = src + (size_t)l * K_ * N_;
    unsigned short* d = dst + (size_t)l * N_ * Kdst;
    int tx = threadIdx.x & 31, ty = threadIdx.x >> 5;
#pragma unroll
    for (int i = 0; i < 32; i += 8)
        tile[ty + i][tx] = s[(size_t)(k0 + ty + i) * N_ + n0 + tx];
    __syncthreads();
#pragma unroll
    for (int i = 0; i < 32; i += 8) {
        int n = n0 + ty + i;
        float sc = scale ? scale[(size_t)l * N_ + n] * BNS : 1.f;
        d[(size_t)n * Kdst + koff + k0 + tx] = f2b(tile[tx][ty + i] * sc);
    }
}

// ---------------------------------------------------------------------------
__global__ void k_mkvec(const float* __restrict__ bn1_g, const float* __restrict__ bn1_b,
                        const float* __restrict__ bn2_g, const float* __restrict__ bn2_b,
                        const float* __restrict__ bn3_g, const float* __restrict__ bn3_b,
                        const float* __restrict__ gb2, const float* __restrict__ aob,
                        const float* __restrict__ mb2,
                        float* __restrict__ biasC, float* __restrict__ rC,
                        float* __restrict__ biasF, float* __restrict__ rF) {
    int i = blockIdx.x * 256 + threadIdx.x;
    float s1 = bn1_g[i] * BNS, t1 = bn1_b[i];
    float s2 = bn2_g[i] * BNS, t2 = bn2_b[i];
    float s3 = bn3_g[i] * BNS, t3 = bn3_b[i];
    biasC[i] = gb2[i] * s1 + t1 + aob[i] * s2 + t2;
    rC[i]    = s1 + s2;
    biasF[i] = mb2[i] * s3 + t3;
    rF[i]    = s3;
}

// ---------------------------------------------------------------------------
// GINE aggregation + fused g1 GEMM.
// Phase 1: stage graph h (128 KB LDS), aggregate z for the block's 128 nodes
//          into registers (packed bf16).
// Phase 2: store z into LDS [128][256] bf16 with quad-XOR swizzle, then
//          hid = relu(z @ W1 + b1) via MFMA (A from LDS, B from L2-resident
//          w_g1), written to comb2[:, 0:256] (ldc 512).
// ---------------------------------------------------------------------------
__global__ __launch_bounds__(1024)
void k_gine_g1(const unsigned short* __restrict__ hb,
               const int* __restrict__ rowptr, const uint2* __restrict__ epk,
               const float* __restrict__ ew, const float* __restrict__ eb,
               const unsigned short* __restrict__ w1,  // [256 n][256 k] bf16
               const float* __restrict__ b1,
               unsigned short* __restrict__ hid) {     // ldc 512
    __shared__ unsigned short lds_h[NNODE * DMODEL];   // 128 KB
    int g = blockIdx.x >> 1, half = blockIdx.x & 1;
    int t = threadIdx.x;

    const unsigned short* gsrc = hb + (size_t)g * NNODE * DMODEL;
#pragma unroll
    for (int i = 0; i < 8; ++i) {
        int slot = i * 1024 + t;
        __builtin_amdgcn_global_load_lds(
            (const __attribute__((address_space(1))) void*)(gsrc + slot * 8),
            (__attribute__((address_space(3))) void*)&lds_h[slot * 8], 16, 0, 0);
    }
    asm volatile("s_waitcnt vmcnt(0)" ::: "memory");
    __syncthreads();

    int w = t >> 6, lane = t & 63;
    int d0 = lane * 4;
    float4 ew4 = *(const float4*)&ew[d0];
    float4 eb4 = *(const float4*)&eb[d0];

    const int* rp = rowptr + g * (NNODE + 1);
    int ln0 = half * 128 + w * 8;
    unsigned int zlo[8], zhi[8];
#pragma unroll 1
    for (int i = 0; i < 8; ++i) {
        int ln = ln0 + i;
        int beg = rp[ln], end = rp[ln + 1];
        float a0 = 0.f, a1 = 0.f, a2 = 0.f, a3 = 0.f;
        for (int c = beg; c < end; c += 64) {
            int cnt = min(64, end - c);
            int sl_ = 0, avb_ = 0;
            if (lane < cnt) {
                uint2 r = epk[c + lane];
                sl_  = (int)(r.x & 0xffffu);
                avb_ = (int)r.y;
            }
#pragma unroll 4
            for (int ii = 0; ii < cnt; ++ii) {
                int   sl = __builtin_amdgcn_readlane(sl_, ii);
                float av = __int_as_float(__builtin_amdgcn_readlane(avb_, ii));
                uint2 hv = *(const uint2*)&lds_h[sl * DMODEL + d0];
                float t0 = fmaf(av, ew4.x, eb4.x);
                float t1 = fmaf(av, ew4.y, eb4.y);
                float t2 = fmaf(av, ew4.z, eb4.z);
                float t3 = fmaf(av, ew4.w, eb4.w);
                a0 += fmaxf(__uint_as_float(hv.x << 16) + t0, 0.f);
                a1 += fmaxf(__uint_as_float(hv.x & 0xffff0000u) + t1, 0.f);
                a2 += fmaxf(__uint_as_float(hv.y << 16) + t2, 0.f);
                a3 += fmaxf(__uint_as_float(hv.y & 0xffff0000u) + t3, 0.f);
            }
        }
        uint2 hv = *(const uint2*)&lds_h[ln * DMODEL + d0];
        float z0 = __uint_as_float(hv.x << 16)         + a0;
        float z1 = __uint_as_float(hv.x & 0xffff0000u) + a1;
        float z2 = __uint_as_float(hv.y << 16)         + a2;
        float z3 = __uint_as_float(hv.y & 0xffff0000u) + a3;
        asm("v_cvt_pk_bf16_f32 %0, %1, %2" : "=v"(zlo[i]) : "v"(z0), "v"(z1));
        asm("v_cvt_pk_bf16_f32 %0, %1, %2" : "=v"(zhi[i]) : "v"(z2), "v"(z3));
    }
    __syncthreads();   // all waves done reading h

    // ---- store z (bf16) into LDS [128][256], quad-XOR swizzled ----
    char* zs = (char*)lds_h;   // 64 KB region
#pragma unroll
    for (int i = 0; i < 8; ++i) {
        int r = w * 8 + i;                       // local row 0..127
        int pq = (lane >> 1) ^ (r & 7);          // physical quad
        uint2 pk; pk.x = zlo[i]; pk.y = zhi[i];
        *(uint2*)(zs + r * 512 + (pq << 4) + ((lane & 1) << 3)) = pk;
    }
    __syncthreads();

    // ---- GEMM: hid[128 x 256] = relu(z @ W1 + b1) ----
    int wr2 = w >> 3, wc2 = w & 7;               // 2 x 8 wave grid, tile 64x32
    int rl = lane & 15, kc = lane >> 4;
    f32x4 acc[4][2] = {};
#pragma unroll
    for (int kq = 0; kq < 8; ++kq) {             // K step = 32
        bf16x8 av[4], bv[2];
#pragma unroll
        for (int mm = 0; mm < 4; ++mm) {
            int r = wr2 * 64 + mm * 16 + rl;
            int pq = (kq * 4 + kc) ^ (r & 7);
            av[mm] = *(const bf16x8*)(zs + r * 512 + (pq << 4));
        }
#pragma unroll
        for (int nn = 0; nn < 2; ++nn) {
            int nrow = wc2 * 32 + nn * 16 + rl;
            bv[nn] = *(const bf16x8*)(w1 + (size_t)nrow * 256 + kq * 32 + kc * 8);
        }
        __builtin_amdgcn_s_setprio(1);
#pragma unroll
        for (int mm = 0; mm < 4; ++mm)
#pragma unroll
            for (int nn = 0; nn < 2; ++nn)
                acc[mm][nn] = __builtin_amdgcn_mfma_f32_16x16x32_bf16(av[mm], bv[nn], acc[mm][nn], 0, 0, 0);
        __builtin_amdgcn_s_setprio(0);
    }
    int rh = lane >> 4;
    size_t rowbase = (size_t)g * NNODE + half * 128;
#pragma unroll
    for (int nn = 0; nn < 2; ++nn) {
        int col = wc2 * 32 + nn * 16 + rl;
        float bb = b1[col];
#pragma unroll
        for (int mm = 0; mm < 4; ++mm) {
#pragma unroll
            for (int j = 0; j < 4; ++j) {
                int r = wr2 * 64 + mm * 16 + rh * 4 + j;
                float v = fmaxf(acc[mm][nn][j] + bb, 0.f);
                hid[(rowbase + r) * 512 + col] = f2b(v);
            }
        }
    }
}

// ---------------------------------------------------------------------------
// bf16 MFMA GEMM, BK=64 + chunk-XOR swizzle (unchanged from round 6).
// MODE 0: +bias   1: relu(+bias)   4: +bias + rvec[col]*res_bf16[row,col]
// ---------------------------------------------------------------------------
template <int MODE>
__global__ __launch_bounds__(256)
void k_mm(const unsigned short* __restrict__ A, const unsigned short* __restrict__ Bt,
          const float* __restrict__ bias, const float* __restrict__ rvec,
          const unsigned short* __restrict__ resb, float* __restrict__ Cf,
          unsigned short* __restrict__ Cb, int M, int N, int K, int ldc) {
    const int BM = 128, BN = 128, BK = 64;
    __shared__ unsigned short As[BM * BK];
    __shared__ unsigned short Bs[BN * BK];

    int t = threadIdx.x;
    int w = t >> 6, l = t & 63;
    int wr = w >> 1, wc = w & 1;
    int bm = blockIdx.y * BM, bn = blockIdx.x * BN;

    f32x4 acc[4][4] = {};
    int rl = l & 15, kc = l >> 4;

    for (int k0 = 0; k0 < K; k0 += BK) {
#pragma unroll
        for (int i = 0; i < 4; ++i) {
            int slot = i * 256 + t;
            int row = slot >> 3, pc = slot & 7;
            int lc = pc ^ (row & 7);
            const unsigned short* gp = A + (size_t)(bm + row) * K + k0 + lc * 8;
            __builtin_amdgcn_global_load_lds(
                (const __attribute__((address_space(1))) void*)gp,
                (__attribute__((address_space(3))) void*)&As[(i * 256 + w * 64) * 8],
                16, 0, 0);
        }
#pragma unroll
        for (int i = 0; i < 4; ++i) {
            int slot = i * 256 + t;
            int row = slot >> 3, pc = slot & 7;
            int lc = pc ^ (row & 7);
            const unsigned short* gp = Bt + (size_t)(bn + row) * K + k0 + lc * 8;
            __builtin_amdgcn_global_load_lds(
                (const __attribute__((address_space(1))) void*)gp,
                (__attribute__((address_space(3))) void*)&Bs[(i * 256 + w * 64) * 8],
                16, 0, 0);
        }
        asm volatile("s_waitcnt vmcnt(0)" ::: "memory");
        __syncthreads();

#pragma unroll
        for (int kk = 0; kk < 2; ++kk) {
            int lch = kk * 4 + kc;
            bf16x8 av[4], bv[4];
#pragma unroll
            for (int m = 0; m < 4; ++m) {
                int r = wr * 64 + m * 16 + rl;
                av[m] = *(const bf16x8*)&As[r * BK + ((lch ^ (r & 7)) << 3)];
            }
#pragma unroll
            for (int n = 0; n < 4; ++n) {
                int r = wc * 64 + n * 16 + rl;
                bv[n] = *(const bf16x8*)&Bs[r * BK + ((lch ^ (r & 7)) << 3)];
            }
#pragma unroll
            for (int m = 0; m < 4; ++m)
#pragma unroll
                for (int n = 0; n < 4; ++n)
                    acc[m][n] = __builtin_amdgcn_mfma_f32_16x16x32_bf16(av[m], bv[n], acc[m][n], 0, 0, 0);
        }
        __syncthreads();
    }

    int rh = l >> 4;
#pragma unroll
    for (int n = 0; n < 4; ++n) {
        int col = bn + wc * 64 + n * 16 + rl;
        float bv_ = bias[col];
        float rv = 0.f;
        if (MODE == 4) rv = rvec[col];
#pragma unroll
        for (int m = 0; m < 4; ++m) {
#pragma unroll
            for (int j = 0; j < 4; ++j) {
                int row = bm + wr * 64 + m * 16 + rh * 4 + j;
                size_t idx = (size_t)row * ldc + col;
                float v = acc[m][n][j] + bv_;
                if (MODE == 1) v = fmaxf(v, 0.f);
                if (MODE == 4) v += rv * b2f(resb[idx]);
                if (Cf) Cf[idx] = v;
                Cb[idx] = f2b(v);
            }
        }
    }
}

// ---------------------------------------------------------------------------
// MFMA attention v2: K read directly from global (L1/L2-resident), no Ks LDS.
// LDS = Vt + Ps = 50.7 KB -> 3 blocks/CU. setprio around MFMA clusters.
// ---------------------------------------------------------------------------
#define VP 264
#define OSTR 512
#define OOFF 256
__global__ __launch_bounds__(256, 3)
void k_attn(const unsigned short* __restrict__ qkv, unsigned short* __restrict__ o) {
    __shared__ unsigned short lds[8448 + 16896];  // Vt [32][264] | Ps 4x[16][264]
    unsigned short* Vt = lds;
    unsigned short* Ps = lds + 8448;

    int bh = blockIdx.x;
    int b = bh >> 3, h = bh & 7;
    int t = threadIdx.x;
    int w = t >> 6, l = t & 63;
    int rl = l & 15, kc = l >> 4;
    const float scale = 0.17677669529663687f; // 1/sqrt(32)

    const unsigned short* base = qkv + (size_t)b * NNODE * (3 * DMODEL);
    const unsigned short* Kbase = base + DMODEL + h * DHEAD;

    // ---- stage V^T: thread t -> keys k0..k0+3, dims d0..d0+7 ----
    {
        int k0 = (t & 63) * 4, d0 = (t >> 6) * 8;
        bf16x8 vr[4];
#pragma unroll
        for (int i = 0; i < 4; ++i)
            vr[i] = *(const bf16x8*)(base + (size_t)(k0 + i) * (3 * DMODEL) + 2 * DMODEL + h * DHEAD + d0);
#pragma unroll
        for (int d = 0; d < 8; ++d) {
            ushort4 pk;
            pk.x = (unsigned short)vr[0][d];
            pk.y = (unsigned short)vr[1][d];
            pk.z = (unsigned short)vr[2][d];
            pk.w = (unsigned short)vr[3][d];
            *(ushort4*)&Vt[(d0 + d) * VP + k0] = pk;
        }
    }

    // ---- Q fragments (B-operand) ----
    bf16x8 qv[4];
#pragma unroll
    for (int m = 0; m < 4; ++m) {
        int q = w * 64 + m * 16 + rl;
        qv[m] = *(const bf16x8*)(base + (size_t)q * (3 * DMODEL) + h * DHEAD + kc * 8);
    }
    __syncthreads();

    unsigned short* Pw = Ps + w * 16 * VP;
    f32x4 zero = {0.f, 0.f, 0.f, 0.f};

#pragma unroll 1
    for (int m = 0; m < 4; ++m) {
        // ---- S^T tiles: K fragments from global, grouped 4-wide ----
        f32x4 s[16];
#pragma unroll
        for (int g4 = 0; g4 < 4; ++g4) {
            bf16x8 kv[4];
#pragma unroll
            for (int i = 0; i < 4; ++i)
                kv[i] = *(const bf16x8*)(Kbase + (size_t)((g4 * 4 + i) * 16 + rl) * (3 * DMODEL) + kc * 8);
            __builtin_amdgcn_s_setprio(1);
#pragma unroll
            for (int i = 0; i < 4; ++i)
                s[g4 * 4 + i] = __builtin_amdgcn_mfma_f32_16x16x32_bf16(kv[i], qv[m], zero, 0, 0, 0);
            __builtin_amdgcn_s_setprio(0);
        }
        // ---- softmax row q=rl ----
        float mv = -1e30f;
#pragma unroll
        for (int n = 0; n < 16; ++n)
#pragma unroll
            for (int j = 0; j < 4; ++j) mv = fmaxf(mv, s[n][j]);
        mv = fmaxf(mv, __shfl_xor(mv, 16));
        mv = fmaxf(mv, __shfl_xor(mv, 32));
        float nb = -mv * scale;
        float sumv = 0.f;
#pragma unroll
        for (int n = 0; n < 16; ++n) {
            float p0 = __expf(fmaf(s[n][0], scale, nb));
            float p1 = __expf(fmaf(s[n][1], scale, nb));
            float p2 = __expf(fmaf(s[n][2], scale, nb));
            float p3 = __expf(fmaf(s[n][3], scale, nb));
            sumv += (p0 + p1) + (p2 + p3);
            unsigned int lo, hi;
            asm("v_cvt_pk_bf16_f32 %0, %1, %2" : "=v"(lo) : "v"(p0), "v"(p1));
            asm("v_cvt_pk_bf16_f32 %0, %1, %2" : "=v"(hi) : "v"(p2), "v"(p3));
            uint2 pk; pk.x = lo; pk.y = hi;
            *(uint2*)&Pw[rl * VP + n * 16 + kc * 4] = pk;
        }
        sumv += __shfl_xor(sumv, 16);
        sumv += __shfl_xor(sumv, 32);

        // ---- O = P V ----
        f32x4 o0 = zero, o1 = zero;
#pragma unroll
        for (int ks = 0; ks < 8; ++ks) {
            bf16x8 pa = *(const bf16x8*)&Pw[rl * VP + ks * 32 + kc * 8];
            bf16x8 v0 = *(const bf16x8*)&Vt[rl * VP + ks * 32 + kc * 8];
            bf16x8 v1 = *(const bf16x8*)&Vt[(16 + rl) * VP + ks * 32 + kc * 8];
            __builtin_amdgcn_s_setprio(1);
            o0 = __builtin_amdgcn_mfma_f32_16x16x32_bf16(pa, v0, o0, 0, 0, 0);
            o1 = __builtin_amdgcn_mfma_f32_16x16x32_bf16(pa, v1, o1, 0, 0, 0);
            __builtin_amdgcn_s_setprio(0);
        }
#pragma unroll
        for (int j = 0; j < 4; ++j) {
            float sj = __shfl(sumv, kc * 4 + j);
            float inv = 1.f / sj;
            int q = w * 64 + m * 16 + kc * 4 + j;
            unsigned short* orow = o + ((size_t)b * NNODE + q) * OSTR + OOFF + h * DHEAD;
            orow[rl]      = f2b(o0[j] * inv);
            orow[16 + rl] = f2b(o1[j] * inv);
        }
    }
}

// ---------------------------------------------------------------------------
extern "C" void kernel_launch(void* const* d_in, const int* in_sizes, int n_in,
                              void* d_out, int out_size, void* d_ws, size_t ws_size,
                              hipStream_t stream) {
    const float* x          = (const float*)d_in[0];
    const float* edge_attr  = (const float*)d_in[1];
    const float* node_w     = (const float*)d_in[2];
    const float* node_b     = (const float*)d_in[3];
    const float* edge_w     = (const float*)d_in[4];
    const float* edge_b     = (const float*)d_in[5];
    const float* gine_w1    = (const float*)d_in[6];
    const float* gine_b1    = (const float*)d_in[7];
    const float* gine_w2    = (const float*)d_in[8];
    const float* gine_b2    = (const float*)d_in[9];
    const float* attn_in_w  = (const float*)d_in[10];
    const float* attn_in_b  = (const float*)d_in[11];
    const float* attn_out_w = (const float*)d_in[12];
    const float* attn_out_b = (const float*)d_in[13];
    const float* mlp_w1     = (const float*)d_in[14];
    const float* mlp_b1     = (const float*)d_in[15];
    const float* mlp_w2     = (const float*)d_in[16];
    const float* mlp_b2     = (const float*)d_in[17];
    const float* bn1_g      = (const float*)d_in[18];
    const float* bn1_b      = (const float*)d_in[19];
    const float* bn2_g      = (const float*)d_in[20];
    const float* bn2_b      = (const float*)d_in[21];
    const float* bn3_g      = (const float*)d_in[22];
    const float* bn3_b      = (const float*)d_in[23];
    const int*   edge_index = (const int*)d_in[24];

    const int* srcp = edge_index;
    const int* dstp = edge_index + EDGES;

    float* out = (float*)d_out;
    char*  ws  = (char*)d_ws;

    // ---- workspace layout ----
    size_t off = 0;
    unsigned short* hb    = (unsigned short*)(ws + off); off += (size_t)NTOT * DMODEL * 2;
    unsigned short* comb2 = (unsigned short*)(ws + off); off += (size_t)NTOT * 512 * 2;   // [hid | o]
    unsigned short* qkvb  = (unsigned short*)(ws + off); off += (size_t)NTOT * 768 * 2;
    unsigned short* cmbb  = (unsigned short*)(ws + off); off += (size_t)NTOT * DMODEL * 2;
    unsigned short* h5b   = (unsigned short*)(ws + off); off += (size_t)NTOT * 512 * 2;
    unsigned short* xb    = (unsigned short*)(ws + off); off += (size_t)NTOT * DIN * 2;
    unsigned short* w_node = (unsigned short*)(ws + off); off += (size_t)DMODEL * DIN * 2;
    unsigned short* w_g1   = (unsigned short*)(ws + off); off += (size_t)NLAYER * DMODEL * DMODEL * 2;
    unsigned short* w_cat  = (unsigned short*)(ws + off); off += (size_t)NLAYER * DMODEL * 512 * 2;
    unsigned short* w_ai   = (unsigned short*)(ws + off); off += (size_t)NLAYER * 3 * DMODEL * DMODEL * 2;
    unsigned short* w_m1   = (unsigned short*)(ws + off); off += (size_t)NLAYER * 2 * DMODEL * DMODEL * 2;
    unsigned short* w_m2s  = (unsigned short*)(ws + off); off += (size_t)NLAYER * DMODEL * 512 * 2;
    float* biasC = (float*)(ws + off); off += (size_t)NLAYER * DMODEL * 4;
    float* rC    = (float*)(ws + off); off += (size_t)NLAYER * DMODEL * 4;
    float* biasF = (float*)(ws + off); off += (size_t)NLAYER * DMODEL * 4;
    float* rF    = (float*)(ws + off); off += (size_t)NLAYER * DMODEL * 4;
    uint2* gbuf  = (uint2*)(ws + off);  off += (size_t)BGRAPH * CAPG * 8;
    uint2* epk   = (uint2*)(ws + off);  off += (size_t)BGRAPH * CAPG * 8;
    int*   gcnt  = (int*)(ws + off);    off += (size_t)BGRAPH * 4;
    int*   rowptr = (int*)(ws + off);   off += (size_t)BGRAPH * (NNODE + 1) * 4;
    (void)ws_size; (void)in_sizes; (void)n_in; (void)out_size;

    // ---- CSR build ----
    hipMemsetAsync(gcnt, 0, (size_t)BGRAPH * 4, stream);
    k_bucket<<<EDGES / 4096, 1024, 0, stream>>>(srcp, dstp, edge_attr, gcnt, gbuf);
    k_gsort<<<BGRAPH, 1024, 0, stream>>>(gbuf, gcnt, epk, rowptr);

    // ---- weight & input conversion ----
    k_f2b<<<NTOT * DIN / 4 / 256, 256, 0, stream>>>(x, xb, NTOT * DIN);
    k_convT<<<dim3(8, 2, 1), 256, 0, stream>>>(node_w, w_node, DIN, DMODEL, nullptr, DIN, 0);
    k_convT<<<dim3(8, 8, NLAYER), 256, 0, stream>>>(gine_w1, w_g1, DMODEL, DMODEL, nullptr, DMODEL, 0);
    k_convT<<<dim3(8, 8, NLAYER), 256, 0, stream>>>(gine_w2, w_cat, DMODEL, DMODEL, bn1_g, 512, 0);
    k_convT<<<dim3(8, 8, NLAYER), 256, 0, stream>>>(attn_out_w, w_cat, DMODEL, DMODEL, bn2_g, 512, 256);
    k_convT<<<dim3(24, 8, NLAYER), 256, 0, stream>>>(attn_in_w, w_ai, DMODEL, 3 * DMODEL, nullptr, DMODEL, 0);
    k_convT<<<dim3(16, 8, NLAYER), 256, 0, stream>>>(mlp_w1, w_m1, DMODEL, 2 * DMODEL, nullptr, DMODEL, 0);
    k_convT<<<dim3(8, 16, NLAYER), 256, 0, stream>>>(mlp_w2, w_m2s, 2 * DMODEL, DMODEL, bn3_g, 512, 0);
    k_mkvec<<<NLAYER, 256, 0, stream>>>(bn1_g, bn1_b, bn2_g, bn2_b, bn3_g, bn3_b,
                                        gine_b2, attn_out_b, mlp_b2, biasC, rC, biasF, rF);

    // ---- encoder: hb = bf16(x @ node_w + node_b) ----
    k_mm<0><<<dim3(2, NTOT / 128), 256, 0, stream>>>(
        xb, w_node, node_b, nullptr, nullptr, nullptr, hb, NTOT, DMODEL, DIN, DMODEL);

    for (int l = 0; l < NLAYER; ++l) {
        const unsigned short* g1 = w_g1 + (size_t)l * DMODEL * DMODEL;
        const unsigned short* wc = w_cat + (size_t)l * DMODEL * 512;
        const unsigned short* ai = w_ai + (size_t)l * 3 * DMODEL * DMODEL;
        const unsigned short* m1 = w_m1 + (size_t)l * 2 * DMODEL * DMODEL;
        const unsigned short* m2 = w_m2s + (size_t)l * DMODEL * 512;

        // GINE aggregate + g1 GEMM fused -> comb2[:, 0:256]
        k_gine_g1<<<BGRAPH * 2, 1024, 0, stream>>>(hb, rowptr, epk, edge_w, edge_b,
                                                   g1, gine_b1 + (size_t)l * DMODEL, comb2);
        // qkv = h @ attn_in_w + b -> qkvb
        k_mm<0><<<dim3(6, NTOT / 128), 256, 0, stream>>>(
            hb, ai, attn_in_b + (size_t)l * 3 * DMODEL, nullptr, nullptr, nullptr,
            qkvb, NTOT, 3 * DMODEL, DMODEL, 3 * DMODEL);
        // attention -> comb2[:, 256:512]
        k_attn<<<BGRAPH * NHEAD, 256, 0, stream>>>(qkvb, comb2);
        // comb = [hid|o] @ [g2*s1; ao*s2] + biasC + rC*h  -> cmbb
        k_mm<4><<<dim3(2, NTOT / 128), 256, 0, stream>>>(
            comb2, wc, biasC + (size_t)l * DMODEL, rC + (size_t)l * DMODEL, hb,
            nullptr, cmbb, NTOT, DMODEL, 512, DMODEL);
        // h5 = relu(comb @ mlp_w1 + b1) -> h5b
        k_mm<1><<<dim3(4, NTOT / 128), 256, 0, stream>>>(
            cmbb, m1, mlp_b1 + (size_t)l * 2 * DMODEL, nullptr, nullptr, nullptr,
            h5b, NTOT, 2 * DMODEL, DMODEL, 2 * DMODEL);
        // h = h5 @ (m2*s3) + biasF + rF*comb -> hb (+ fp32 out on last layer)
        float* dest = (l == NLAYER - 1) ? out : nullptr;
        k_mm<4><<<dim3(2, NTOT / 128), 256, 0, stream>>>(
            h5b, m2, biasF + (size_t)l * DMODEL, rF + (size_t)l * DMODEL, cmbb,
            dest, hb, NTOT, DMODEL, 512, DMODEL);
    }
}

// Round 9
// 919.305 us; speedup vs baseline: 1.4229x; 1.0393x over previous
//
#include <hip/hip_runtime.h>
#include <math.h>

#define NTOT   32768
#define DMODEL 256
#define EDGES  1048576
#define BGRAPH 128
#define NNODE  256
#define NHEAD  8
#define DHEAD  32
#define NLAYER 4
#define DIN    64
#define BNS    0.9999950000374997f   // 1/sqrt(1+1e-5)
#define CAPG   9216                   // per-graph edge bucket capacity

typedef short bf16x8 __attribute__((ext_vector_type(8)));
typedef float f32x4  __attribute__((ext_vector_type(4)));

__device__ __forceinline__ unsigned short f2b(float f) {
    union { float f; unsigned int u; } v; v.f = f;
    unsigned int r = v.u + 0x7FFFu + ((v.u >> 16) & 1u);  // RNE
    return (unsigned short)(r >> 16);
}
__device__ __forceinline__ float b2f(unsigned short u) {
    union { unsigned int u; float f; } v; v.u = ((unsigned int)u) << 16;
    return v.f;
}

// ---------------------------------------------------------------------------
// Pass 1: bucket edges by graph (L2-friendly coarse scatter).
// ---------------------------------------------------------------------------
__global__ __launch_bounds__(1024)
void k_bucket(const int* __restrict__ src, const int* __restrict__ dst,
              const float* __restrict__ ea, int* __restrict__ gcnt,
              uint2* __restrict__ gbuf) {
    __shared__ int hist[BGRAPH], base[BGRAPH], cur[BGRAPH];
    int t = threadIdx.x;
    int e0 = blockIdx.x * 4096;
    if (t < BGRAPH) { hist[t] = 0; cur[t] = 0; }
    __syncthreads();
    int g4[4]; unsigned int m4[4], a4[4];
#pragma unroll
    for (int j = 0; j < 4; ++j) {
        int e = e0 + j * 1024 + t;
        int s = src[e], d = dst[e];
        g4[j] = d >> 8;
        m4[j] = (unsigned int)(s & 255) | ((unsigned int)(d & 255) << 16);
        a4[j] = __float_as_uint(ea[e]);
        atomicAdd(&hist[g4[j]], 1);
    }
    __syncthreads();
    if (t < BGRAPH) base[t] = atomicAdd(&gcnt[t], hist[t]);
    __syncthreads();
#pragma unroll
    for (int j = 0; j < 4; ++j) {
        int g = g4[j];
        int slot = base[g] + atomicAdd(&cur[g], 1);
        if (slot < CAPG) {
            uint2 r; r.x = m4[j]; r.y = a4[j];
            gbuf[(size_t)g * CAPG + slot] = r;
        }
    }
}

// ---------------------------------------------------------------------------
// Pass 2: per-graph LDS counting sort -> CSR records + rowptr.
// ---------------------------------------------------------------------------
__global__ __launch_bounds__(1024)
void k_gsort(const uint2* __restrict__ gbuf, const int* __restrict__ gcnt,
             uint2* __restrict__ epk, int* __restrict__ rowptr) {
    __shared__ int s[NNODE], excl[NNODE + 1], cur[NNODE];
    int g = blockIdx.x;
    int c = gcnt[g];
    int t = threadIdx.x;
    size_t base = (size_t)g * CAPG;
    if (t < NNODE) { s[t] = 0; cur[t] = 0; }
    __syncthreads();
    for (int i = t; i < c; i += 1024)
        atomicAdd(&s[gbuf[base + i].x >> 16], 1);
    __syncthreads();
    for (int o = 1; o < NNODE; o <<= 1) {
        int add = (t < NNODE && t >= o) ? s[t - o] : 0;
        __syncthreads();
        if (t < NNODE) s[t] += add;
        __syncthreads();
    }
    if (t < NNODE) excl[t + 1] = s[t];
    if (t == 0) excl[0] = 0;
    __syncthreads();
    if (t <= NNODE) rowptr[g * (NNODE + 1) + t] = (int)base + excl[t];
    for (int i = t; i < c; i += 1024) {
        uint2 r = gbuf[base + i];
        int dl = r.x >> 16;
        int p = excl[dl] + atomicAdd(&cur[dl], 1);
        epk[base + p] = r;
    }
}

// ---------------------------------------------------------------------------
__global__ void k_f2b(const float* __restrict__ s, unsigned short* __restrict__ d, int n) {
    int i = (blockIdx.x * 256 + threadIdx.x) * 4;
    if (i >= n) return;
    float4 v = *(const float4*)(s + i);
    d[i + 0] = f2b(v.x); d[i + 1] = f2b(v.y); d[i + 2] = f2b(v.z); d[i + 3] = f2b(v.w);
}

// ---------------------------------------------------------------------------
// Weight convert + transpose (+optional BN scale fold)
// ---------------------------------------------------------------------------
__global__ __launch_bounds__(256)
void k_convT(const float* __restrict__ src, unsigned short* __restrict__ dst, int K_, int N_,
             const float* __restrict__ scale, int Kdst, int koff) {
    __shared__ float tile[32][33];
    int l = blockIdx.z;
    int n0 = blockIdx.x * 32, k0 = blockIdx.y * 32;
    const float* s = src + (size_t)l * K_ * N_;
    unsigned short* d = dst + (size_t)l * N_ * Kdst;
    int tx = threadIdx.x & 31, ty = threadIdx.x >> 5;
#pragma unroll
    for (int i = 0; i < 32; i += 8)
        tile[ty + i][tx] = s[(size_t)(k0 + ty + i) * N_ + n0 + tx];
    __syncthreads();
#pragma unroll
    for (int i = 0; i < 32; i += 8) {
        int n = n0 + ty + i;
        float sc = scale ? scale[(size_t)l * N_ + n] * BNS : 1.f;
        d[(size_t)n * Kdst + koff + k0 + tx] = f2b(tile[tx][ty + i] * sc);
    }
}

// ---------------------------------------------------------------------------
__global__ void k_mkvec(const float* __restrict__ bn1_g, const float* __restrict__ bn1_b,
                        const float* __restrict__ bn2_g, const float* __restrict__ bn2_b,
                        const float* __restrict__ bn3_g, const float* __restrict__ bn3_b,
                        const float* __restrict__ gb2, const float* __restrict__ aob,
                        const float* __restrict__ mb2,
                        float* __restrict__ biasC, float* __restrict__ rC,
                        float* __restrict__ biasF, float* __restrict__ rF) {
    int i = blockIdx.x * 256 + threadIdx.x;
    float s1 = bn1_g[i] * BNS, t1 = bn1_b[i];
    float s2 = bn2_g[i] * BNS, t2 = bn2_b[i];
    float s3 = bn3_g[i] * BNS, t3 = bn3_b[i];
    biasC[i] = gb2[i] * s1 + t1 + aob[i] * s2 + t2;
    rC[i]    = s1 + s2;
    biasF[i] = mb2[i] * s3 + t3;
    rF[i]    = s3;
}

// ---------------------------------------------------------------------------
// GINE aggregation + fused g1 GEMM, v2 (no h staging).
// 4 blocks/graph (64 dst nodes each), XCD-swizzled so a graph's blocks share
// one XCD's L2 (h = 128 KB, L2-resident gather). LDS = 32 KB z-tile only ->
// 2 blocks/CU. Each wave owns 4 dst nodes; per edge the wave gathers the src
// row from L2 (coalesced 512 B). Then hid = relu(z @ W1 + b1) via MFMA.
// ---------------------------------------------------------------------------
__global__ __launch_bounds__(1024, 8)
void k_gine_g1(const unsigned short* __restrict__ hb,
               const int* __restrict__ rowptr, const uint2* __restrict__ epk,
               const float* __restrict__ ew, const float* __restrict__ eb,
               const unsigned short* __restrict__ w1,  // [256 n][256 k] bf16
               const float* __restrict__ b1,
               unsigned short* __restrict__ hid) {     // ldc 512
    __shared__ unsigned short zs16[64 * 256];          // 32 KB
    int bid = blockIdx.x;
    int logical = (bid & 7) * (BGRAPH * 4 / 8) + (bid >> 3);   // XCD-chunked
    int g = logical >> 2, q = logical & 3;
    int t = threadIdx.x;
    int w = t >> 6, lane = t & 63;
    int d0 = lane * 4;
    float4 ew4 = *(const float4*)&ew[d0];
    float4 eb4 = *(const float4*)&eb[d0];
    const unsigned short* hg = hb + (size_t)g * NNODE * DMODEL;
    const int* rp = rowptr + g * (NNODE + 1);

    int ln0 = q * 64 + w * 4;
    unsigned int zlo[4], zhi[4];
#pragma unroll 1
    for (int i = 0; i < 4; ++i) {
        int ln = ln0 + i;
        int beg = rp[ln], end = rp[ln + 1];
        float a0 = 0.f, a1 = 0.f, a2 = 0.f, a3 = 0.f;
        for (int c = beg; c < end; c += 64) {
            int cnt = min(64, end - c);
            int sl_ = 0, avb_ = 0;
            if (lane < cnt) {
                uint2 r = epk[c + lane];
                sl_  = (int)(r.x & 0xffffu);
                avb_ = (int)r.y;
            }
#pragma unroll 4
            for (int ii = 0; ii < cnt; ++ii) {
                int   sl = __builtin_amdgcn_readlane(sl_, ii);
                float av = __int_as_float(__builtin_amdgcn_readlane(avb_, ii));
                uint2 hv = *(const uint2*)&hg[(size_t)sl * DMODEL + d0];   // L2 gather
                float t0 = fmaf(av, ew4.x, eb4.x);
                float t1 = fmaf(av, ew4.y, eb4.y);
                float t2 = fmaf(av, ew4.z, eb4.z);
                float t3 = fmaf(av, ew4.w, eb4.w);
                a0 += fmaxf(__uint_as_float(hv.x << 16) + t0, 0.f);
                a1 += fmaxf(__uint_as_float(hv.x & 0xffff0000u) + t1, 0.f);
                a2 += fmaxf(__uint_as_float(hv.y << 16) + t2, 0.f);
                a3 += fmaxf(__uint_as_float(hv.y & 0xffff0000u) + t3, 0.f);
            }
        }
        uint2 hv = *(const uint2*)&hg[(size_t)ln * DMODEL + d0];
        float z0 = __uint_as_float(hv.x << 16)         + a0;
        float z1 = __uint_as_float(hv.x & 0xffff0000u) + a1;
        float z2 = __uint_as_float(hv.y << 16)         + a2;
        float z3 = __uint_as_float(hv.y & 0xffff0000u) + a3;
        asm("v_cvt_pk_bf16_f32 %0, %1, %2" : "=v"(zlo[i]) : "v"(z0), "v"(z1));
        asm("v_cvt_pk_bf16_f32 %0, %1, %2" : "=v"(zhi[i]) : "v"(z2), "v"(z3));
    }

    // ---- store z (bf16) into LDS [64][256], quad-XOR swizzled ----
    char* zs = (char*)zs16;
#pragma unroll
    for (int i = 0; i < 4; ++i) {
        int r = w * 4 + i;                       // local row 0..63
        int pq = (lane >> 1) ^ (r & 7);          // physical quad
        uint2 pk; pk.x = zlo[i]; pk.y = zhi[i];
        *(uint2*)(zs + r * 512 + (pq << 4) + ((lane & 1) << 3)) = pk;
    }
    __syncthreads();

    // ---- GEMM: hid[64 x 256] = relu(z @ W1 + b1); waves 2(M) x 8(N) ----
    int wm = w >> 3, wn = w & 7;
    int rl = lane & 15, kc = lane >> 4;
    f32x4 acc[2][2] = {};
#pragma unroll
    for (int kq = 0; kq < 8; ++kq) {             // K step = 32
        bf16x8 av[2], bv[2];
#pragma unroll
        for (int mm = 0; mm < 2; ++mm) {
            int r = wm * 32 + mm * 16 + rl;
            int pq = (kq * 4 + kc) ^ (r & 7);
            av[mm] = *(const bf16x8*)(zs + r * 512 + (pq << 4));
        }
#pragma unroll
        for (int nn = 0; nn < 2; ++nn) {
            int nrow = wn * 32 + nn * 16 + rl;
            bv[nn] = *(const bf16x8*)(w1 + (size_t)nrow * 256 + kq * 32 + kc * 8);
        }
        __builtin_amdgcn_s_setprio(1);
#pragma unroll
        for (int mm = 0; mm < 2; ++mm)
#pragma unroll
            for (int nn = 0; nn < 2; ++nn)
                acc[mm][nn] = __builtin_amdgcn_mfma_f32_16x16x32_bf16(av[mm], bv[nn], acc[mm][nn], 0, 0, 0);
        __builtin_amdgcn_s_setprio(0);
    }
    int rh = lane >> 4;
    size_t rowbase = (size_t)g * NNODE + q * 64;
#pragma unroll
    for (int nn = 0; nn < 2; ++nn) {
        int col = wn * 32 + nn * 16 + rl;
        float bb = b1[col];
#pragma unroll
        for (int mm = 0; mm < 2; ++mm) {
#pragma unroll
            for (int j = 0; j < 4; ++j) {
                int r = wm * 32 + mm * 16 + rh * 4 + j;
                float v = fmaxf(acc[mm][nn][j] + bb, 0.f);
                hid[(rowbase + r) * 512 + col] = f2b(v);
            }
        }
    }
}

// ---------------------------------------------------------------------------
// bf16 MFMA GEMM, BK=64 + chunk-XOR swizzle + XCD-chunked block swizzle.
// Grid is 1D (gx*gy); logical id x-major so same-A-panel blocks share an XCD.
// MODE 0: +bias   1: relu(+bias)   4: +bias + rvec[col]*res_bf16[row,col]
// ---------------------------------------------------------------------------
template <int MODE>
__global__ __launch_bounds__(256)
void k_mm(const unsigned short* __restrict__ A, const unsigned short* __restrict__ Bt,
          const float* __restrict__ bias, const float* __restrict__ rvec,
          const unsigned short* __restrict__ resb, float* __restrict__ Cf,
          unsigned short* __restrict__ Cb, int M, int N, int K, int ldc, int gx) {
    const int BM = 128, BN = 128, BK = 64;
    __shared__ unsigned short As[BM * BK];
    __shared__ unsigned short Bs[BN * BK];

    int nwg = gridDim.x;
    int bid = blockIdx.x;
    int logical = (bid & 7) * (nwg >> 3) + (bid >> 3);   // XCD-chunked (nwg%8==0)
    int by = logical / gx, bx = logical % gx;

    int t = threadIdx.x;
    int w = t >> 6, l = t & 63;
    int wr = w >> 1, wc = w & 1;
    int bm = by * BM, bn = bx * BN;

    f32x4 acc[4][4] = {};
    int rl = l & 15, kc = l >> 4;

    for (int k0 = 0; k0 < K; k0 += BK) {
#pragma unroll
        for (int i = 0; i < 4; ++i) {
            int slot = i * 256 + t;
            int row = slot >> 3, pc = slot & 7;
            int lc = pc ^ (row & 7);
            const unsigned short* gp = A + (size_t)(bm + row) * K + k0 + lc * 8;
            __builtin_amdgcn_global_load_lds(
                (const __attribute__((address_space(1))) void*)gp,
                (__attribute__((address_space(3))) void*)&As[(i * 256 + w * 64) * 8],
                16, 0, 0);
        }
#pragma unroll
        for (int i = 0; i < 4; ++i) {
            int slot = i * 256 + t;
            int row = slot >> 3, pc = slot & 7;
            int lc = pc ^ (row & 7);
            const unsigned short* gp = Bt + (size_t)(bn + row) * K + k0 + lc * 8;
            __builtin_amdgcn_global_load_lds(
                (const __attribute__((address_space(1))) void*)gp,
                (__attribute__((address_space(3))) void*)&Bs[(i * 256 + w * 64) * 8],
                16, 0, 0);
        }
        asm volatile("s_waitcnt vmcnt(0)" ::: "memory");
        __syncthreads();

#pragma unroll
        for (int kk = 0; kk < 2; ++kk) {
            int lch = kk * 4 + kc;
            bf16x8 av[4], bv[4];
#pragma unroll
            for (int m = 0; m < 4; ++m) {
                int r = wr * 64 + m * 16 + rl;
                av[m] = *(const bf16x8*)&As[r * BK + ((lch ^ (r & 7)) << 3)];
            }
#pragma unroll
            for (int n = 0; n < 4; ++n) {
                int r = wc * 64 + n * 16 + rl;
                bv[n] = *(const bf16x8*)&Bs[r * BK + ((lch ^ (r & 7)) << 3)];
            }
#pragma unroll
            for (int m = 0; m < 4; ++m)
#pragma unroll
                for (int n = 0; n < 4; ++n)
                    acc[m][n] = __builtin_amdgcn_mfma_f32_16x16x32_bf16(av[m], bv[n], acc[m][n], 0, 0, 0);
        }
        __syncthreads();
    }

    int rh = l >> 4;
#pragma unroll
    for (int n = 0; n < 4; ++n) {
        int col = bn + wc * 64 + n * 16 + rl;
        float bv_ = bias[col];
        float rv = 0.f;
        if (MODE == 4) rv = rvec[col];
#pragma unroll
        for (int m = 0; m < 4; ++m) {
#pragma unroll
            for (int j = 0; j < 4; ++j) {
                int row = bm + wr * 64 + m * 16 + rh * 4 + j;
                size_t idx = (size_t)row * ldc + col;
                float v = acc[m][n][j] + bv_;
                if (MODE == 1) v = fmaxf(v, 0.f);
                if (MODE == 4) v += rv * b2f(resb[idx]);
                if (Cf) Cf[idx] = v;
                Cb[idx] = f2b(v);
            }
        }
    }
}

// ---------------------------------------------------------------------------
// MFMA attention v2: K read directly from global (L1/L2-resident), no Ks LDS.
// LDS = Vt + Ps = 50.7 KB -> 3 blocks/CU. setprio around MFMA clusters.
// ---------------------------------------------------------------------------
#define VP 264
#define OSTR 512
#define OOFF 256
__global__ __launch_bounds__(256, 3)
void k_attn(const unsigned short* __restrict__ qkv, unsigned short* __restrict__ o) {
    __shared__ unsigned short lds[8448 + 16896];  // Vt [32][264] | Ps 4x[16][264]
    unsigned short* Vt = lds;
    unsigned short* Ps = lds + 8448;

    int bh = blockIdx.x;
    int b = bh >> 3, h = bh & 7;
    int t = threadIdx.x;
    int w = t >> 6, l = t & 63;
    int rl = l & 15, kc = l >> 4;
    const float scale = 0.17677669529663687f; // 1/sqrt(32)

    const unsigned short* base = qkv + (size_t)b * NNODE * (3 * DMODEL);
    const unsigned short* Kbase = base + DMODEL + h * DHEAD;

    {
        int k0 = (t & 63) * 4, d0 = (t >> 6) * 8;
        bf16x8 vr[4];
#pragma unroll
        for (int i = 0; i < 4; ++i)
            vr[i] = *(const bf16x8*)(base + (size_t)(k0 + i) * (3 * DMODEL) + 2 * DMODEL + h * DHEAD + d0);
#pragma unroll
        for (int d = 0; d < 8; ++d) {
            ushort4 pk;
            pk.x = (unsigned short)vr[0][d];
            pk.y = (unsigned short)vr[1][d];
            pk.z = (unsigned short)vr[2][d];
            pk.w = (unsigned short)vr[3][d];
            *(ushort4*)&Vt[(d0 + d) * VP + k0] = pk;
        }
    }

    bf16x8 qv[4];
#pragma unroll
    for (int m = 0; m < 4; ++m) {
        int q = w * 64 + m * 16 + rl;
        qv[m] = *(const bf16x8*)(base + (size_t)q * (3 * DMODEL) + h * DHEAD + kc * 8);
    }
    __syncthreads();

    unsigned short* Pw = Ps + w * 16 * VP;
    f32x4 zero = {0.f, 0.f, 0.f, 0.f};

#pragma unroll 1
    for (int m = 0; m < 4; ++m) {
        f32x4 s[16];
#pragma unroll
        for (int g4 = 0; g4 < 4; ++g4) {
            bf16x8 kv[4];
#pragma unroll
            for (int i = 0; i < 4; ++i)
                kv[i] = *(const bf16x8*)(Kbase + (size_t)((g4 * 4 + i) * 16 + rl) * (3 * DMODEL) + kc * 8);
            __builtin_amdgcn_s_setprio(1);
#pragma unroll
            for (int i = 0; i < 4; ++i)
                s[g4 * 4 + i] = __builtin_amdgcn_mfma_f32_16x16x32_bf16(kv[i], qv[m], zero, 0, 0, 0);
            __builtin_amdgcn_s_setprio(0);
        }
        float mv = -1e30f;
#pragma unroll
        for (int n = 0; n < 16; ++n)
#pragma unroll
            for (int j = 0; j < 4; ++j) mv = fmaxf(mv, s[n][j]);
        mv = fmaxf(mv, __shfl_xor(mv, 16));
        mv = fmaxf(mv, __shfl_xor(mv, 32));
        float nb = -mv * scale;
        float sumv = 0.f;
#pragma unroll
        for (int n = 0; n < 16; ++n) {
            float p0 = __expf(fmaf(s[n][0], scale, nb));
            float p1 = __expf(fmaf(s[n][1], scale, nb));
            float p2 = __expf(fmaf(s[n][2], scale, nb));
            float p3 = __expf(fmaf(s[n][3], scale, nb));
            sumv += (p0 + p1) + (p2 + p3);
            unsigned int lo, hi;
            asm("v_cvt_pk_bf16_f32 %0, %1, %2" : "=v"(lo) : "v"(p0), "v"(p1));
            asm("v_cvt_pk_bf16_f32 %0, %1, %2" : "=v"(hi) : "v"(p2), "v"(p3));
            uint2 pk; pk.x = lo; pk.y = hi;
            *(uint2*)&Pw[rl * VP + n * 16 + kc * 4] = pk;
        }
        sumv += __shfl_xor(sumv, 16);
        sumv += __shfl_xor(sumv, 32);

        f32x4 o0 = zero, o1 = zero;
#pragma unroll
        for (int ks = 0; ks < 8; ++ks) {
            bf16x8 pa = *(const bf16x8*)&Pw[rl * VP + ks * 32 + kc * 8];
            bf16x8 v0 = *(const bf16x8*)&Vt[rl * VP + ks * 32 + kc * 8];
            bf16x8 v1 = *(const bf16x8*)&Vt[(16 + rl) * VP + ks * 32 + kc * 8];
            __builtin_amdgcn_s_setprio(1);
            o0 = __builtin_amdgcn_mfma_f32_16x16x32_bf16(pa, v0, o0, 0, 0, 0);
            o1 = __builtin_amdgcn_mfma_f32_16x16x32_bf16(pa, v1, o1, 0, 0, 0);
            __builtin_amdgcn_s_setprio(0);
        }
#pragma unroll
        for (int j = 0; j < 4; ++j) {
            float sj = __shfl(sumv, kc * 4 + j);
            float inv = 1.f / sj;
            int q = w * 64 + m * 16 + kc * 4 + j;
            unsigned short* orow = o + ((size_t)b * NNODE + q) * OSTR + OOFF + h * DHEAD;
            orow[rl]      = f2b(o0[j] * inv);
            orow[16 + rl] = f2b(o1[j] * inv);
        }
    }
}

// ---------------------------------------------------------------------------
extern "C" void kernel_launch(void* const* d_in, const int* in_sizes, int n_in,
                              void* d_out, int out_size, void* d_ws, size_t ws_size,
                              hipStream_t stream) {
    const float* x          = (const float*)d_in[0];
    const float* edge_attr  = (const float*)d_in[1];
    const float* node_w     = (const float*)d_in[2];
    const float* node_b     = (const float*)d_in[3];
    const float* edge_w     = (const float*)d_in[4];
    const float* edge_b     = (const float*)d_in[5];
    const float* gine_w1    = (const float*)d_in[6];
    const float* gine_b1    = (const float*)d_in[7];
    const float* gine_w2    = (const float*)d_in[8];
    const float* gine_b2    = (const float*)d_in[9];
    const float* attn_in_w  = (const float*)d_in[10];
    const float* attn_in_b  = (const float*)d_in[11];
    const float* attn_out_w = (const float*)d_in[12];
    const float* attn_out_b = (const float*)d_in[13];
    const float* mlp_w1     = (const float*)d_in[14];
    const float* mlp_b1     = (const float*)d_in[15];
    const float* mlp_w2     = (const float*)d_in[16];
    const float* mlp_b2     = (const float*)d_in[17];
    const float* bn1_g      = (const float*)d_in[18];
    const float* bn1_b      = (const float*)d_in[19];
    const float* bn2_g      = (const float*)d_in[20];
    const float* bn2_b      = (const float*)d_in[21];
    const float* bn3_g      = (const float*)d_in[22];
    const float* bn3_b      = (const float*)d_in[23];
    const int*   edge_index = (const int*)d_in[24];

    const int* srcp = edge_index;
    const int* dstp = edge_index + EDGES;

    float* out = (float*)d_out;
    char*  ws  = (char*)d_ws;

    // ---- workspace layout ----
    size_t off = 0;
    unsigned short* hb    = (unsigned short*)(ws + off); off += (size_t)NTOT * DMODEL * 2;
    unsigned short* comb2 = (unsigned short*)(ws + off); off += (size_t)NTOT * 512 * 2;   // [hid | o]
    unsigned short* qkvb  = (unsigned short*)(ws + off); off += (size_t)NTOT * 768 * 2;
    unsigned short* cmbb  = (unsigned short*)(ws + off); off += (size_t)NTOT * DMODEL * 2;
    unsigned short* h5b   = (unsigned short*)(ws + off); off += (size_t)NTOT * 512 * 2;
    unsigned short* xb    = (unsigned short*)(ws + off); off += (size_t)NTOT * DIN * 2;
    unsigned short* w_node = (unsigned short*)(ws + off); off += (size_t)DMODEL * DIN * 2;
    unsigned short* w_g1   = (unsigned short*)(ws + off); off += (size_t)NLAYER * DMODEL * DMODEL * 2;
    unsigned short* w_cat  = (unsigned short*)(ws + off); off += (size_t)NLAYER * DMODEL * 512 * 2;
    unsigned short* w_ai   = (unsigned short*)(ws + off); off += (size_t)NLAYER * 3 * DMODEL * DMODEL * 2;
    unsigned short* w_m1   = (unsigned short*)(ws + off); off += (size_t)NLAYER * 2 * DMODEL * DMODEL * 2;
    unsigned short* w_m2s  = (unsigned short*)(ws + off); off += (size_t)NLAYER * DMODEL * 512 * 2;
    float* biasC = (float*)(ws + off); off += (size_t)NLAYER * DMODEL * 4;
    float* rC    = (float*)(ws + off); off += (size_t)NLAYER * DMODEL * 4;
    float* biasF = (float*)(ws + off); off += (size_t)NLAYER * DMODEL * 4;
    float* rF    = (float*)(ws + off); off += (size_t)NLAYER * DMODEL * 4;
    uint2* gbuf  = (uint2*)(ws + off);  off += (size_t)BGRAPH * CAPG * 8;
    uint2* epk   = (uint2*)(ws + off);  off += (size_t)BGRAPH * CAPG * 8;
    int*   gcnt  = (int*)(ws + off);    off += (size_t)BGRAPH * 4;
    int*   rowptr = (int*)(ws + off);   off += (size_t)BGRAPH * (NNODE + 1) * 4;
    (void)ws_size; (void)in_sizes; (void)n_in; (void)out_size;

    // ---- CSR build ----
    hipMemsetAsync(gcnt, 0, (size_t)BGRAPH * 4, stream);
    k_bucket<<<EDGES / 4096, 1024, 0, stream>>>(srcp, dstp, edge_attr, gcnt, gbuf);
    k_gsort<<<BGRAPH, 1024, 0, stream>>>(gbuf, gcnt, epk, rowptr);

    // ---- weight & input conversion ----
    k_f2b<<<NTOT * DIN / 4 / 256, 256, 0, stream>>>(x, xb, NTOT * DIN);
    k_convT<<<dim3(8, 2, 1), 256, 0, stream>>>(node_w, w_node, DIN, DMODEL, nullptr, DIN, 0);
    k_convT<<<dim3(8, 8, NLAYER), 256, 0, stream>>>(gine_w1, w_g1, DMODEL, DMODEL, nullptr, DMODEL, 0);
    k_convT<<<dim3(8, 8, NLAYER), 256, 0, stream>>>(gine_w2, w_cat, DMODEL, DMODEL, bn1_g, 512, 0);
    k_convT<<<dim3(8, 8, NLAYER), 256, 0, stream>>>(attn_out_w, w_cat, DMODEL, DMODEL, bn2_g, 512, 256);
    k_convT<<<dim3(24, 8, NLAYER), 256, 0, stream>>>(attn_in_w, w_ai, DMODEL, 3 * DMODEL, nullptr, DMODEL, 0);
    k_convT<<<dim3(16, 8, NLAYER), 256, 0, stream>>>(mlp_w1, w_m1, DMODEL, 2 * DMODEL, nullptr, DMODEL, 0);
    k_convT<<<dim3(8, 16, NLAYER), 256, 0, stream>>>(mlp_w2, w_m2s, 2 * DMODEL, DMODEL, bn3_g, 512, 0);
    k_mkvec<<<NLAYER, 256, 0, stream>>>(bn1_g, bn1_b, bn2_g, bn2_b, bn3_g, bn3_b,
                                        gine_b2, attn_out_b, mlp_b2, biasC, rC, biasF, rF);

    // ---- encoder: hb = bf16(x @ node_w + node_b) ----
    k_mm<0><<<2 * (NTOT / 128), 256, 0, stream>>>(
        xb, w_node, node_b, nullptr, nullptr, nullptr, hb, NTOT, DMODEL, DIN, DMODEL, 2);

    for (int l = 0; l < NLAYER; ++l) {
        const unsigned short* g1 = w_g1 + (size_t)l * DMODEL * DMODEL;
        const unsigned short* wc = w_cat + (size_t)l * DMODEL * 512;
        const unsigned short* ai = w_ai + (size_t)l * 3 * DMODEL * DMODEL;
        const unsigned short* m1 = w_m1 + (size_t)l * 2 * DMODEL * DMODEL;
        const unsigned short* m2 = w_m2s + (size_t)l * DMODEL * 512;

        // GINE aggregate + g1 GEMM fused -> comb2[:, 0:256]
        k_gine_g1<<<BGRAPH * 4, 1024, 0, stream>>>(hb, rowptr, epk, edge_w, edge_b,
                                                   g1, gine_b1 + (size_t)l * DMODEL, comb2);
        // qkv = h @ attn_in_w + b -> qkvb
        k_mm<0><<<6 * (NTOT / 128), 256, 0, stream>>>(
            hb, ai, attn_in_b + (size_t)l * 3 * DMODEL, nullptr, nullptr, nullptr,
            qkvb, NTOT, 3 * DMODEL, DMODEL, 3 * DMODEL, 6);
        // attention -> comb2[:, 256:512]
        k_attn<<<BGRAPH * NHEAD, 256, 0, stream>>>(qkvb, comb2);
        // comb = [hid|o] @ [g2*s1; ao*s2] + biasC + rC*h  -> cmbb
        k_mm<4><<<2 * (NTOT / 128), 256, 0, stream>>>(
            comb2, wc, biasC + (size_t)l * DMODEL, rC + (size_t)l * DMODEL, hb,
            nullptr, cmbb, NTOT, DMODEL, 512, DMODEL, 2);
        // h5 = relu(comb @ mlp_w1 + b1) -> h5b
        k_mm<1><<<4 * (NTOT / 128), 256, 0, stream>>>(
            cmbb, m1, mlp_b1 + (size_t)l * 2 * DMODEL, nullptr, nullptr, nullptr,
            h5b, NTOT, 2 * DMODEL, DMODEL, 2 * DMODEL, 4);
        // h = h5 @ (m2*s3) + biasF + rF*comb -> hb (+ fp32 out on last layer)
        float* dest = (l == NLAYER - 1) ? out : nullptr;
        k_mm<4><<<2 * (NTOT / 128), 256, 0, stream>>>(
            h5b, m2, biasF + (size_t)l * DMODEL, rF + (size_t)l * DMODEL, cmbb,
            dest, hb, NTOT, DMODEL, 512, DMODEL, 2);
    }
}

// Round 10
// 835.884 us; speedup vs baseline: 1.5649x; 1.0998x over previous
//
#include <hip/hip_runtime.h>
#include <math.h>

#define NTOT   32768
#define DMODEL 256
#define EDGES  1048576
#define BGRAPH 128
#define NNODE  256
#define NHEAD  8
#define DHEAD  32
#define NLAYER 4
#define DIN    64
#define BNS    0.9999950000374997f   // 1/sqrt(1+1e-5)
#define CAPG   9216                   // per-graph edge bucket capacity

typedef short bf16x8 __attribute__((ext_vector_type(8)));
typedef float f32x4  __attribute__((ext_vector_type(4)));

__device__ __forceinline__ unsigned short f2b(float f) {
    union { float f; unsigned int u; } v; v.f = f;
    unsigned int r = v.u + 0x7FFFu + ((v.u >> 16) & 1u);  // RNE
    return (unsigned short)(r >> 16);
}
__device__ __forceinline__ float b2f(unsigned short u) {
    union { unsigned int u; float f; } v; v.u = ((unsigned int)u) << 16;
    return v.f;
}

// ---------------------------------------------------------------------------
// Pass 1: bucket edges by graph (L2-friendly coarse scatter).
// ---------------------------------------------------------------------------
__global__ __launch_bounds__(1024)
void k_bucket(const int* __restrict__ src, const int* __restrict__ dst,
              const float* __restrict__ ea, int* __restrict__ gcnt,
              uint2* __restrict__ gbuf) {
    __shared__ int hist[BGRAPH], base[BGRAPH], cur[BGRAPH];
    int t = threadIdx.x;
    int e0 = blockIdx.x * 4096;
    if (t < BGRAPH) { hist[t] = 0; cur[t] = 0; }
    __syncthreads();
    int g4[4]; unsigned int m4[4], a4[4];
#pragma unroll
    for (int j = 0; j < 4; ++j) {
        int e = e0 + j * 1024 + t;
        int s = src[e], d = dst[e];
        g4[j] = d >> 8;
        m4[j] = (unsigned int)(s & 255) | ((unsigned int)(d & 255) << 16);
        a4[j] = __float_as_uint(ea[e]);
        atomicAdd(&hist[g4[j]], 1);
    }
    __syncthreads();
    if (t < BGRAPH) base[t] = atomicAdd(&gcnt[t], hist[t]);
    __syncthreads();
#pragma unroll
    for (int j = 0; j < 4; ++j) {
        int g = g4[j];
        int slot = base[g] + atomicAdd(&cur[g], 1);
        if (slot < CAPG) {
            uint2 r; r.x = m4[j]; r.y = a4[j];
            gbuf[(size_t)g * CAPG + slot] = r;
        }
    }
}

// ---------------------------------------------------------------------------
// Pass 2: per-graph LDS counting sort -> CSR records + rowptr.
// ---------------------------------------------------------------------------
__global__ __launch_bounds__(1024)
void k_gsort(const uint2* __restrict__ gbuf, const int* __restrict__ gcnt,
             uint2* __restrict__ epk, int* __restrict__ rowptr) {
    __shared__ int s[NNODE], excl[NNODE + 1], cur[NNODE];
    int g = blockIdx.x;
    int c = gcnt[g];
    int t = threadIdx.x;
    size_t base = (size_t)g * CAPG;
    if (t < NNODE) { s[t] = 0; cur[t] = 0; }
    __syncthreads();
    for (int i = t; i < c; i += 1024)
        atomicAdd(&s[gbuf[base + i].x >> 16], 1);
    __syncthreads();
    for (int o = 1; o < NNODE; o <<= 1) {
        int add = (t < NNODE && t >= o) ? s[t - o] : 0;
        __syncthreads();
        if (t < NNODE) s[t] += add;
        __syncthreads();
    }
    if (t < NNODE) excl[t + 1] = s[t];
    if (t == 0) excl[0] = 0;
    __syncthreads();
    if (t <= NNODE) rowptr[g * (NNODE + 1) + t] = (int)base + excl[t];
    for (int i = t; i < c; i += 1024) {
        uint2 r = gbuf[base + i];
        int dl = r.x >> 16;
        int p = excl[dl] + atomicAdd(&cur[dl], 1);
        epk[base + p] = r;
    }
}

// ---------------------------------------------------------------------------
// Merged prologue: all weight convert+transpose jobs + mkvec + x->bf16.
// Job table (32x32 tiles): [0,16) node_w | [16,272) g1 | [272,528) g2->cat
// [528,784) ao->cat(+256) | [784,1552) ai | [1552,2064) m1 | [2064,2576) m2s
// [2576,2580) mkvec | [2580,4628) f2b.
// ---------------------------------------------------------------------------
__global__ __launch_bounds__(256)
void k_convall(const float* __restrict__ node_w, const float* __restrict__ gine_w1,
               const float* __restrict__ gine_w2, const float* __restrict__ attn_out_w,
               const float* __restrict__ attn_in_w, const float* __restrict__ mlp_w1,
               const float* __restrict__ mlp_w2,
               const float* __restrict__ bn1_g, const float* __restrict__ bn1_b,
               const float* __restrict__ bn2_g, const float* __restrict__ bn2_b,
               const float* __restrict__ bn3_g, const float* __restrict__ bn3_b,
               const float* __restrict__ gb2, const float* __restrict__ aob,
               const float* __restrict__ mb2, const float* __restrict__ x,
               unsigned short* __restrict__ w_node, unsigned short* __restrict__ w_g1,
               unsigned short* __restrict__ w_cat, unsigned short* __restrict__ w_ai,
               unsigned short* __restrict__ w_m1, unsigned short* __restrict__ w_m2s,
               float* __restrict__ biasC, float* __restrict__ rC,
               float* __restrict__ biasF, float* __restrict__ rF,
               unsigned short* __restrict__ xb) {
    __shared__ float tile[32][33];
    int bid = blockIdx.x;
    int t = threadIdx.x;

    if (bid >= 2580) {                        // f2b: x -> xb (bf16)
        int i = ((bid - 2580) * 256 + t) * 4;
        float4 v = *(const float4*)(x + i);
        xb[i + 0] = f2b(v.x); xb[i + 1] = f2b(v.y);
        xb[i + 2] = f2b(v.z); xb[i + 3] = f2b(v.w);
        return;
    }
    if (bid >= 2576) {                        // mkvec
        int i = (bid - 2576) * 256 + t;
        float s1 = bn1_g[i] * BNS, t1 = bn1_b[i];
        float s2 = bn2_g[i] * BNS, t2 = bn2_b[i];
        float s3 = bn3_g[i] * BNS, t3 = bn3_b[i];
        biasC[i] = gb2[i] * s1 + t1 + aob[i] * s2 + t2;
        rC[i]    = s1 + s2;
        biasF[i] = mb2[i] * s3 + t3;
        rF[i]    = s3;
        return;
    }
    const float* src; unsigned short* dst; const float* scale;
    int K_, N_, Kdst, koff, tx, ty, local;
    if (bid < 16)        { local = bid;      src = node_w;     dst = w_node; scale = nullptr; K_ = 64;  N_ = 256; Kdst = 64;  koff = 0;   tx = 8;  ty = 2;  }
    else if (bid < 272)  { local = bid-16;   src = gine_w1;    dst = w_g1;   scale = nullptr; K_ = 256; N_ = 256; Kdst = 256; koff = 0;   tx = 8;  ty = 8;  }
    else if (bid < 528)  { local = bid-272;  src = gine_w2;    dst = w_cat;  scale = bn1_g;   K_ = 256; N_ = 256; Kdst = 512; koff = 0;   tx = 8;  ty = 8;  }
    else if (bid < 784)  { local = bid-528;  src = attn_out_w; dst = w_cat;  scale = bn2_g;   K_ = 256; N_ = 256; Kdst = 512; koff = 256; tx = 8;  ty = 8;  }
    else if (bid < 1552) { local = bid-784;  src = attn_in_w;  dst = w_ai;   scale = nullptr; K_ = 256; N_ = 768; Kdst = 256; koff = 0;   tx = 24; ty = 8;  }
    else if (bid < 2064) { local = bid-1552; src = mlp_w1;     dst = w_m1;   scale = nullptr; K_ = 256; N_ = 512; Kdst = 256; koff = 0;   tx = 16; ty = 8;  }
    else                 { local = bid-2064; src = mlp_w2;     dst = w_m2s;  scale = bn3_g;   K_ = 512; N_ = 256; Kdst = 512; koff = 0;   tx = 8;  ty = 16; }
    int per = tx * ty;
    int l = local / per;
    int rem = local - l * per;
    int kyt = rem / tx, nxt = rem - kyt * tx;
    int n0 = nxt * 32, k0 = kyt * 32;
    const float* s = src + (size_t)l * K_ * N_;
    unsigned short* d = dst + (size_t)l * N_ * Kdst;
    int tx2 = t & 31, ty2 = t >> 5;
#pragma unroll
    for (int i = 0; i < 32; i += 8)
        tile[ty2 + i][tx2] = s[(size_t)(k0 + ty2 + i) * N_ + n0 + tx2];
    __syncthreads();
#pragma unroll
    for (int i = 0; i < 32; i += 8) {
        int n = n0 + ty2 + i;
        float sc = scale ? scale[(size_t)l * N_ + n] * BNS : 1.f;
        d[(size_t)n * Kdst + koff + k0 + tx2] = f2b(tile[tx2][ty2 + i] * sc);
    }
}

// ---------------------------------------------------------------------------
// GINE aggregation + fused g1 GEMM, v3.
// Structure: 2 blocks/graph x 1024 thr; full-graph h staged in LDS (128 KB).
// Edge metadata broadcast via per-wave LDS scratch + same-address ds_read_b64
// (no readlane, no SGPR hazards, 32-bit addressing only).
// Then hid = relu(z @ W1 + b1) via MFMA, z in quad-XOR-swizzled LDS overlay.
// ---------------------------------------------------------------------------
__global__ __launch_bounds__(1024)
void k_gine_g1(const unsigned short* __restrict__ hb,
               const int* __restrict__ rowptr, const uint2* __restrict__ epk,
               const float* __restrict__ ew, const float* __restrict__ eb,
               const unsigned short* __restrict__ w1,  // [256 n][256 k] bf16
               const float* __restrict__ b1,
               unsigned short* __restrict__ hid) {     // ldc 512
    __shared__ unsigned short lds_h[NNODE * DMODEL];   // 128 KB
    __shared__ uint2 mscr[16][64];                     // 8 KB per-wave scratch
    int g = blockIdx.x >> 1, half = blockIdx.x & 1;
    int t = threadIdx.x;

    const unsigned short* gsrc = hb + (size_t)g * NNODE * DMODEL;
#pragma unroll
    for (int i = 0; i < 8; ++i) {
        int slot = i * 1024 + t;
        __builtin_amdgcn_global_load_lds(
            (const __attribute__((address_space(1))) void*)(gsrc + slot * 8),
            (__attribute__((address_space(3))) void*)&lds_h[slot * 8], 16, 0, 0);
    }
    asm volatile("s_waitcnt vmcnt(0)" ::: "memory");
    __syncthreads();

    int w = t >> 6, lane = t & 63;
    int d0 = lane * 4;
    float4 ew4 = *(const float4*)&ew[d0];
    float4 eb4 = *(const float4*)&eb[d0];
    uint2* ms = mscr[w];

    const int* rp = rowptr + g * (NNODE + 1);
    int ln0 = half * 128 + w * 8;
    unsigned int zlo[8], zhi[8];
#pragma unroll 1
    for (int i = 0; i < 8; ++i) {
        int ln = ln0 + i;
        int beg = rp[ln], end = rp[ln + 1];
        float a0 = 0.f, a1 = 0.f, a2 = 0.f, a3 = 0.f;
        for (int c = beg; c < end; c += 64) {
            int cnt = min(64, end - c);
            if (lane < cnt) ms[lane] = epk[c + lane];
            asm volatile("s_waitcnt lgkmcnt(0)" ::: "memory");
#pragma unroll 4
            for (int ii = 0; ii < cnt; ++ii) {
                uint2 rec = ms[ii];                       // same addr -> broadcast
                int   sl  = (int)(rec.x & 0xffffu);
                float av  = __uint_as_float(rec.y);
                uint2 hv = *(const uint2*)&lds_h[sl * DMODEL + d0];
                float t0 = fmaf(av, ew4.x, eb4.x);
                float t1 = fmaf(av, ew4.y, eb4.y);
                float t2 = fmaf(av, ew4.z, eb4.z);
                float t3 = fmaf(av, ew4.w, eb4.w);
                a0 += fmaxf(__uint_as_float(hv.x << 16) + t0, 0.f);
                a1 += fmaxf(__uint_as_float(hv.x & 0xffff0000u) + t1, 0.f);
                a2 += fmaxf(__uint_as_float(hv.y << 16) + t2, 0.f);
                a3 += fmaxf(__uint_as_float(hv.y & 0xffff0000u) + t3, 0.f);
            }
        }
        uint2 hv = *(const uint2*)&lds_h[ln * DMODEL + d0];
        float z0 = __uint_as_float(hv.x << 16)         + a0;
        float z1 = __uint_as_float(hv.x & 0xffff0000u) + a1;
        float z2 = __uint_as_float(hv.y << 16)         + a2;
        float z3 = __uint_as_float(hv.y & 0xffff0000u) + a3;
        asm("v_cvt_pk_bf16_f32 %0, %1, %2" : "=v"(zlo[i]) : "v"(z0), "v"(z1));
        asm("v_cvt_pk_bf16_f32 %0, %1, %2" : "=v"(zhi[i]) : "v"(z2), "v"(z3));
    }
    __syncthreads();   // all waves done reading h

    // ---- store z (bf16) into LDS [128][256] overlay, quad-XOR swizzled ----
    char* zs = (char*)lds_h;   // 64 KB region
#pragma unroll
    for (int i = 0; i < 8; ++i) {
        int r = w * 8 + i;                       // local row 0..127
        int pq = (lane >> 1) ^ (r & 7);          // physical quad
        uint2 pk; pk.x = zlo[i]; pk.y = zhi[i];
        *(uint2*)(zs + r * 512 + (pq << 4) + ((lane & 1) << 3)) = pk;
    }
    __syncthreads();

    // ---- GEMM: hid[128 x 256] = relu(z @ W1 + b1); waves 2(M) x 8(N) ----
    int wr2 = w >> 3, wc2 = w & 7;
    int rl = lane & 15, kc = lane >> 4;
    f32x4 acc[4][2] = {};
#pragma unroll
    for (int kq = 0; kq < 8; ++kq) {             // K step = 32
        bf16x8 av[4], bv[2];
#pragma unroll
        for (int mm = 0; mm < 4; ++mm) {
            int r = wr2 * 64 + mm * 16 + rl;
            int pq = (kq * 4 + kc) ^ (r & 7);
            av[mm] = *(const bf16x8*)(zs + r * 512 + (pq << 4));
        }
#pragma unroll
        for (int nn = 0; nn < 2; ++nn) {
            int nrow = wc2 * 32 + nn * 16 + rl;
            bv[nn] = *(const bf16x8*)(w1 + (size_t)nrow * 256 + kq * 32 + kc * 8);
        }
        __builtin_amdgcn_s_setprio(1);
#pragma unroll
        for (int mm = 0; mm < 4; ++mm)
#pragma unroll
            for (int nn = 0; nn < 2; ++nn)
                acc[mm][nn] = __builtin_amdgcn_mfma_f32_16x16x32_bf16(av[mm], bv[nn], acc[mm][nn], 0, 0, 0);
        __builtin_amdgcn_s_setprio(0);
    }
    int rh = lane >> 4;
    size_t rowbase = (size_t)g * NNODE + half * 128;
#pragma unroll
    for (int nn = 0; nn < 2; ++nn) {
        int col = wc2 * 32 + nn * 16 + rl;
        float bb = b1[col];
#pragma unroll
        for (int mm = 0; mm < 4; ++mm) {
#pragma unroll
            for (int j = 0; j < 4; ++j) {
                int r = wr2 * 64 + mm * 16 + rh * 4 + j;
                float v = fmaxf(acc[mm][nn][j] + bb, 0.f);
                hid[(rowbase + r) * 512 + col] = f2b(v);
            }
        }
    }
}

// ---------------------------------------------------------------------------
// bf16 MFMA GEMM, BK=64 + chunk-XOR swizzle + XCD-chunked block swizzle.
// MODE 0: +bias   1: relu(+bias)   4: +bias + rvec[col]*res_bf16[row,col]
// ---------------------------------------------------------------------------
template <int MODE>
__global__ __launch_bounds__(256)
void k_mm(const unsigned short* __restrict__ A, const unsigned short* __restrict__ Bt,
          const float* __restrict__ bias, const float* __restrict__ rvec,
          const unsigned short* __restrict__ resb, float* __restrict__ Cf,
          unsigned short* __restrict__ Cb, int M, int N, int K, int ldc, int gx) {
    const int BM = 128, BN = 128, BK = 64;
    __shared__ unsigned short As[BM * BK];
    __shared__ unsigned short Bs[BN * BK];

    int nwg = gridDim.x;
    int bid = blockIdx.x;
    int logical = (bid & 7) * (nwg >> 3) + (bid >> 3);   // XCD-chunked (nwg%8==0)
    int by = logical / gx, bx = logical % gx;

    int t = threadIdx.x;
    int w = t >> 6, l = t & 63;
    int wr = w >> 1, wc = w & 1;
    int bm = by * BM, bn = bx * BN;

    f32x4 acc[4][4] = {};
    int rl = l & 15, kc = l >> 4;

    for (int k0 = 0; k0 < K; k0 += BK) {
#pragma unroll
        for (int i = 0; i < 4; ++i) {
            int slot = i * 256 + t;
            int row = slot >> 3, pc = slot & 7;
            int lc = pc ^ (row & 7);
            const unsigned short* gp = A + (size_t)(bm + row) * K + k0 + lc * 8;
            __builtin_amdgcn_global_load_lds(
                (const __attribute__((address_space(1))) void*)gp,
                (__attribute__((address_space(3))) void*)&As[(i * 256 + w * 64) * 8],
                16, 0, 0);
        }
#pragma unroll
        for (int i = 0; i < 4; ++i) {
            int slot = i * 256 + t;
            int row = slot >> 3, pc = slot & 7;
            int lc = pc ^ (row & 7);
            const unsigned short* gp = Bt + (size_t)(bn + row) * K + k0 + lc * 8;
            __builtin_amdgcn_global_load_lds(
                (const __attribute__((address_space(1))) void*)gp,
                (__attribute__((address_space(3))) void*)&Bs[(i * 256 + w * 64) * 8],
                16, 0, 0);
        }
        asm volatile("s_waitcnt vmcnt(0)" ::: "memory");
        __syncthreads();

#pragma unroll
        for (int kk = 0; kk < 2; ++kk) {
            int lch = kk * 4 + kc;
            bf16x8 av[4], bv[4];
#pragma unroll
            for (int m = 0; m < 4; ++m) {
                int r = wr * 64 + m * 16 + rl;
                av[m] = *(const bf16x8*)&As[r * BK + ((lch ^ (r & 7)) << 3)];
            }
#pragma unroll
            for (int n = 0; n < 4; ++n) {
                int r = wc * 64 + n * 16 + rl;
                bv[n] = *(const bf16x8*)&Bs[r * BK + ((lch ^ (r & 7)) << 3)];
            }
#pragma unroll
            for (int m = 0; m < 4; ++m)
#pragma unroll
                for (int n = 0; n < 4; ++n)
                    acc[m][n] = __builtin_amdgcn_mfma_f32_16x16x32_bf16(av[m], bv[n], acc[m][n], 0, 0, 0);
        }
        __syncthreads();
    }

    int rh = l >> 4;
#pragma unroll
    for (int n = 0; n < 4; ++n) {
        int col = bn + wc * 64 + n * 16 + rl;
        float bv_ = bias[col];
        float rv = 0.f;
        if (MODE == 4) rv = rvec[col];
#pragma unroll
        for (int m = 0; m < 4; ++m) {
#pragma unroll
            for (int j = 0; j < 4; ++j) {
                int row = bm + wr * 64 + m * 16 + rh * 4 + j;
                size_t idx = (size_t)row * ldc + col;
                float v = acc[m][n][j] + bv_;
                if (MODE == 1) v = fmaxf(v, 0.f);
                if (MODE == 4) v += rv * b2f(resb[idx]);
                if (Cf) Cf[idx] = v;
                Cb[idx] = f2b(v);
            }
        }
    }
}

// ---------------------------------------------------------------------------
// MFMA attention v2: K read directly from global (L1/L2-resident), no Ks LDS.
// LDS = Vt + Ps = 50.7 KB -> 3 blocks/CU. setprio around MFMA clusters.
// ---------------------------------------------------------------------------
#define VP 264
#define OSTR 512
#define OOFF 256
__global__ __launch_bounds__(256, 3)
void k_attn(const unsigned short* __restrict__ qkv, unsigned short* __restrict__ o) {
    __shared__ unsigned short lds[8448 + 16896];  // Vt [32][264] | Ps 4x[16][264]
    unsigned short* Vt = lds;
    unsigned short* Ps = lds + 8448;

    int bh = blockIdx.x;
    int b = bh >> 3, h = bh & 7;
    int t = threadIdx.x;
    int w = t >> 6, l = t & 63;
    int rl = l & 15, kc = l >> 4;
    const float scale = 0.17677669529663687f; // 1/sqrt(32)

    const unsigned short* base = qkv + (size_t)b * NNODE * (3 * DMODEL);
    const unsigned short* Kbase = base + DMODEL + h * DHEAD;

    {
        int k0 = (t & 63) * 4, d0 = (t >> 6) * 8;
        bf16x8 vr[4];
#pragma unroll
        for (int i = 0; i < 4; ++i)
            vr[i] = *(const bf16x8*)(base + (size_t)(k0 + i) * (3 * DMODEL) + 2 * DMODEL + h * DHEAD + d0);
#pragma unroll
        for (int d = 0; d < 8; ++d) {
            ushort4 pk;
            pk.x = (unsigned short)vr[0][d];
            pk.y = (unsigned short)vr[1][d];
            pk.z = (unsigned short)vr[2][d];
            pk.w = (unsigned short)vr[3][d];
            *(ushort4*)&Vt[(d0 + d) * VP + k0] = pk;
        }
    }

    bf16x8 qv[4];
#pragma unroll
    for (int m = 0; m < 4; ++m) {
        int q = w * 64 + m * 16 + rl;
        qv[m] = *(const bf16x8*)(base + (size_t)q * (3 * DMODEL) + h * DHEAD + kc * 8);
    }
    __syncthreads();

    unsigned short* Pw = Ps + w * 16 * VP;
    f32x4 zero = {0.f, 0.f, 0.f, 0.f};

#pragma unroll 1
    for (int m = 0; m < 4; ++m) {
        f32x4 s[16];
#pragma unroll
        for (int g4 = 0; g4 < 4; ++g4) {
            bf16x8 kv[4];
#pragma unroll
            for (int i = 0; i < 4; ++i)
                kv[i] = *(const bf16x8*)(Kbase + (size_t)((g4 * 4 + i) * 16 + rl) * (3 * DMODEL) + kc * 8);
            __builtin_amdgcn_s_setprio(1);
#pragma unroll
            for (int i = 0; i < 4; ++i)
                s[g4 * 4 + i] = __builtin_amdgcn_mfma_f32_16x16x32_bf16(kv[i], qv[m], zero, 0, 0, 0);
            __builtin_amdgcn_s_setprio(0);
        }
        float mv = -1e30f;
#pragma unroll
        for (int n = 0; n < 16; ++n)
#pragma unroll
            for (int j = 0; j < 4; ++j) mv = fmaxf(mv, s[n][j]);
        mv = fmaxf(mv, __shfl_xor(mv, 16));
        mv = fmaxf(mv, __shfl_xor(mv, 32));
        float nb = -mv * scale;
        float sumv = 0.f;
#pragma unroll
        for (int n = 0; n < 16; ++n) {
            float p0 = __expf(fmaf(s[n][0], scale, nb));
            float p1 = __expf(fmaf(s[n][1], scale, nb));
            float p2 = __expf(fmaf(s[n][2], scale, nb));
            float p3 = __expf(fmaf(s[n][3], scale, nb));
            sumv += (p0 + p1) + (p2 + p3);
            unsigned int lo, hi;
            asm("v_cvt_pk_bf16_f32 %0, %1, %2" : "=v"(lo) : "v"(p0), "v"(p1));
            asm("v_cvt_pk_bf16_f32 %0, %1, %2" : "=v"(hi) : "v"(p2), "v"(p3));
            uint2 pk; pk.x = lo; pk.y = hi;
            *(uint2*)&Pw[rl * VP + n * 16 + kc * 4] = pk;
        }
        sumv += __shfl_xor(sumv, 16);
        sumv += __shfl_xor(sumv, 32);

        f32x4 o0 = zero, o1 = zero;
#pragma unroll
        for (int ks = 0; ks < 8; ++ks) {
            bf16x8 pa = *(const bf16x8*)&Pw[rl * VP + ks * 32 + kc * 8];
            bf16x8 v0 = *(const bf16x8*)&Vt[rl * VP + ks * 32 + kc * 8];
            bf16x8 v1 = *(const bf16x8*)&Vt[(16 + rl) * VP + ks * 32 + kc * 8];
            __builtin_amdgcn_s_setprio(1);
            o0 = __builtin_amdgcn_mfma_f32_16x16x32_bf16(pa, v0, o0, 0, 0, 0);
            o1 = __builtin_amdgcn_mfma_f32_16x16x32_bf16(pa, v1, o1, 0, 0, 0);
            __builtin_amdgcn_s_setprio(0);
        }
#pragma unroll
        for (int j = 0; j < 4; ++j) {
            float sj = __shfl(sumv, kc * 4 + j);
            float inv = 1.f / sj;
            int q = w * 64 + m * 16 + kc * 4 + j;
            unsigned short* orow = o + ((size_t)b * NNODE + q) * OSTR + OOFF + h * DHEAD;
            orow[rl]      = f2b(o0[j] * inv);
            orow[16 + rl] = f2b(o1[j] * inv);
        }
    }
}

// ---------------------------------------------------------------------------
extern "C" void kernel_launch(void* const* d_in, const int* in_sizes, int n_in,
                              void* d_out, int out_size, void* d_ws, size_t ws_size,
                              hipStream_t stream) {
    const float* x          = (const float*)d_in[0];
    const float* edge_attr  = (const float*)d_in[1];
    const float* node_w     = (const float*)d_in[2];
    const float* node_b     = (const float*)d_in[3];
    const float* edge_w     = (const float*)d_in[4];
    const float* edge_b     = (const float*)d_in[5];
    const float* gine_w1    = (const float*)d_in[6];
    const float* gine_b1    = (const float*)d_in[7];
    const float* gine_w2    = (const float*)d_in[8];
    const float* gine_b2    = (const float*)d_in[9];
    const float* attn_in_w  = (const float*)d_in[10];
    const float* attn_in_b  = (const float*)d_in[11];
    const float* attn_out_w = (const float*)d_in[12];
    const float* attn_out_b = (const float*)d_in[13];
    const float* mlp_w1     = (const float*)d_in[14];
    const float* mlp_b1     = (const float*)d_in[15];
    const float* mlp_w2     = (const float*)d_in[16];
    const float* mlp_b2     = (const float*)d_in[17];
    const float* bn1_g      = (const float*)d_in[18];
    const float* bn1_b      = (const float*)d_in[19];
    const float* bn2_g      = (const float*)d_in[20];
    const float* bn2_b      = (const float*)d_in[21];
    const float* bn3_g      = (const float*)d_in[22];
    const float* bn3_b      = (const float*)d_in[23];
    const int*   edge_index = (const int*)d_in[24];

    const int* srcp = edge_index;
    const int* dstp = edge_index + EDGES;

    float* out = (float*)d_out;
    char*  ws  = (char*)d_ws;

    // ---- workspace layout ----
    size_t off = 0;
    unsigned short* hb    = (unsigned short*)(ws + off); off += (size_t)NTOT * DMODEL * 2;
    unsigned short* comb2 = (unsigned short*)(ws + off); off += (size_t)NTOT * 512 * 2;   // [hid | o]
    unsigned short* qkvb  = (unsigned short*)(ws + off); off += (size_t)NTOT * 768 * 2;
    unsigned short* cmbb  = (unsigned short*)(ws + off); off += (size_t)NTOT * DMODEL * 2;
    unsigned short* h5b   = (unsigned short*)(ws + off); off += (size_t)NTOT * 512 * 2;
    unsigned short* xb    = (unsigned short*)(ws + off); off += (size_t)NTOT * DIN * 2;
    unsigned short* w_node = (unsigned short*)(ws + off); off += (size_t)DMODEL * DIN * 2;
    unsigned short* w_g1   = (unsigned short*)(ws + off); off += (size_t)NLAYER * DMODEL * DMODEL * 2;
    unsigned short* w_cat  = (unsigned short*)(ws + off); off += (size_t)NLAYER * DMODEL * 512 * 2;
    unsigned short* w_ai   = (unsigned short*)(ws + off); off += (size_t)NLAYER * 3 * DMODEL * DMODEL * 2;
    unsigned short* w_m1   = (unsigned short*)(ws + off); off += (size_t)NLAYER * 2 * DMODEL * DMODEL * 2;
    unsigned short* w_m2s  = (unsigned short*)(ws + off); off += (size_t)NLAYER * DMODEL * 512 * 2;
    float* biasC = (float*)(ws + off); off += (size_t)NLAYER * DMODEL * 4;
    float* rC    = (float*)(ws + off); off += (size_t)NLAYER * DMODEL * 4;
    float* biasF = (float*)(ws + off); off += (size_t)NLAYER * DMODEL * 4;
    float* rF    = (float*)(ws + off); off += (size_t)NLAYER * DMODEL * 4;
    uint2* gbuf  = (uint2*)(ws + off);  off += (size_t)BGRAPH * CAPG * 8;
    uint2* epk   = (uint2*)(ws + off);  off += (size_t)BGRAPH * CAPG * 8;
    int*   gcnt  = (int*)(ws + off);    off += (size_t)BGRAPH * 4;
    int*   rowptr = (int*)(ws + off);   off += (size_t)BGRAPH * (NNODE + 1) * 4;
    (void)ws_size; (void)in_sizes; (void)n_in; (void)out_size;

    // ---- CSR build ----
    hipMemsetAsync(gcnt, 0, (size_t)BGRAPH * 4, stream);
    k_bucket<<<EDGES / 4096, 1024, 0, stream>>>(srcp, dstp, edge_attr, gcnt, gbuf);
    k_gsort<<<BGRAPH, 1024, 0, stream>>>(gbuf, gcnt, epk, rowptr);

    // ---- merged weight/input conversion + epilogue vectors ----
    k_convall<<<4628, 256, 0, stream>>>(node_w, gine_w1, gine_w2, attn_out_w,
                                        attn_in_w, mlp_w1, mlp_w2,
                                        bn1_g, bn1_b, bn2_g, bn2_b, bn3_g, bn3_b,
                                        gine_b2, attn_out_b, mlp_b2, x,
                                        w_node, w_g1, w_cat, w_ai, w_m1, w_m2s,
                                        biasC, rC, biasF, rF, xb);

    // ---- encoder: hb = bf16(x @ node_w + node_b) ----
    k_mm<0><<<2 * (NTOT / 128), 256, 0, stream>>>(
        xb, w_node, node_b, nullptr, nullptr, nullptr, hb, NTOT, DMODEL, DIN, DMODEL, 2);

    for (int l = 0; l < NLAYER; ++l) {
        const unsigned short* g1 = w_g1 + (size_t)l * DMODEL * DMODEL;
        const unsigned short* wc = w_cat + (size_t)l * DMODEL * 512;
        const unsigned short* ai = w_ai + (size_t)l * 3 * DMODEL * DMODEL;
        const unsigned short* m1 = w_m1 + (size_t)l * 2 * DMODEL * DMODEL;
        const unsigned short* m2 = w_m2s + (size_t)l * DMODEL * 512;

        // GINE aggregate + g1 GEMM fused -> comb2[:, 0:256]
        k_gine_g1<<<BGRAPH * 2, 1024, 0, stream>>>(hb, rowptr, epk, edge_w, edge_b,
                                                   g1, gine_b1 + (size_t)l * DMODEL, comb2);
        // qkv = h @ attn_in_w + b -> qkvb
        k_mm<0><<<6 * (NTOT / 128), 256, 0, stream>>>(
            hb, ai, attn_in_b + (size_t)l * 3 * DMODEL, nullptr, nullptr, nullptr,
            qkvb, NTOT, 3 * DMODEL, DMODEL, 3 * DMODEL, 6);
        // attention -> comb2[:, 256:512]
        k_attn<<<BGRAPH * NHEAD, 256, 0, stream>>>(qkvb, comb2);
        // comb = [hid|o] @ [g2*s1; ao*s2] + biasC + rC*h  -> cmbb
        k_mm<4><<<2 * (NTOT / 128), 256, 0, stream>>>(
            comb2, wc, biasC + (size_t)l * DMODEL, rC + (size_t)l * DMODEL, hb,
            nullptr, cmbb, NTOT, DMODEL, 512, DMODEL, 2);
        // h5 = relu(comb @ mlp_w1 + b1) -> h5b
        k_mm<1><<<4 * (NTOT / 128), 256, 0, stream>>>(
            cmbb, m1, mlp_b1 + (size_t)l * 2 * DMODEL, nullptr, nullptr, nullptr,
            h5b, NTOT, 2 * DMODEL, DMODEL, 2 * DMODEL, 4);
        // h = h5 @ (m2*s3) + biasF + rF*comb -> hb (+ fp32 out on last layer)
        float* dest = (l == NLAYER - 1) ? out : nullptr;
        k_mm<4><<<2 * (NTOT / 128), 256, 0, stream>>>(
            h5b, m2, biasF + (size_t)l * DMODEL, rF + (size_t)l * DMODEL, cmbb,
            dest, hb, NTOT, DMODEL, 512, DMODEL, 2);
    }
}